// Round 1
// baseline (889.771 us; speedup 1.0000x reference)
//
#include <hip/hip_runtime.h>
#include <hip/hip_bf16.h>

typedef __bf16 bf16x8 __attribute__((ext_vector_type(8)));
typedef float f32x4 __attribute__((ext_vector_type(4)));

#define D_FEAT 64
#define HID 128
#define BE 128
#define LSTR 136   // 128 + 8 pad: row stride 272B (16B-aligned, 2-way bank max)

static __device__ __forceinline__ unsigned fkey(float f) {
    unsigned u = __float_as_uint(f);
    return (u & 0x80000000u) ? ~u : (u | 0x80000000u);
}
static __device__ __forceinline__ float funkey(unsigned k) {
    unsigned u = (k & 0x80000000u) ? (k & 0x7fffffffu) : ~k;
    return __uint_as_float(u);
}

__global__ void k_init(const float* __restrict__ prev, float* __restrict__ out,
                       __bf16* __restrict__ featb, unsigned* __restrict__ gmax,
                       float* __restrict__ gsum, int total, int N)
{
    int i = blockIdx.x * 256 + threadIdx.x;
    if (i < total) {
        float v = prev[i];
        out[i] = v;
        featb[i] = (__bf16)v;
    }
    if (i < N) { gmax[i] = 0u; gsum[i] = 0.f; }
}

// transpose+convert weights: gw1t[c][k]=gw1[k][c] (128x128), mw1t same, mw2t[c][k]=mw2[k][c] (64 cols x 128 k)
__global__ void k_wconv(const float* __restrict__ gw1, const float* __restrict__ mw1,
                        const float* __restrict__ mw2,
                        __bf16* __restrict__ gw1t, __bf16* __restrict__ mw1t,
                        __bf16* __restrict__ mw2t)
{
    int i = blockIdx.x * 256 + threadIdx.x;
    if (i < 16384) {
        int c = i >> 7, k = i & 127;
        gw1t[i] = (__bf16)gw1[k * 128 + c];
    } else if (i < 32768) {
        int j = i - 16384; int c = j >> 7, k = j & 127;
        mw1t[j] = (__bf16)mw1[k * 128 + c];
    } else if (i < 40960) {
        int j = i - 32768; int c = j >> 7, k = j & 127;
        mw2t[j] = (__bf16)mw2[k * 64 + c];
    }
}

__global__ void __launch_bounds__(256, 2)
k_gate(const __bf16* __restrict__ feat,
       const int* __restrict__ selfi, const int* __restrict__ nbri,
       const __bf16* __restrict__ w1t, const float* __restrict__ b1,
       const float* __restrict__ w2, const float* __restrict__ b2,
       float* __restrict__ logit_out, unsigned* __restrict__ gmax, int E)
{
    __shared__ __align__(16) __bf16 lds_msg[BE][LSTR];
    __shared__ __align__(16) __bf16 lds_w[HID][LSTR];
    const int tid = threadIdx.x;
    const int e0 = blockIdx.x * BE;

    // stage msg tile: 128 edges x [self(64)|nbr(64)] bf16
    {
        const int edge = tid >> 1, half = tid & 1;
        const int ge = e0 + edge;
        int node = 0;
        if (ge < E) node = half ? nbri[ge] : selfi[ge];
        const uint4* src = reinterpret_cast<const uint4*>(feat + (size_t)node * D_FEAT);
        uint4* dst = reinterpret_cast<uint4*>(&lds_msg[edge][half * 64]);
        #pragma unroll
        for (int j = 0; j < 8; ++j) dst[j] = src[j];
    }
    // stage w1t (128x128 bf16 = 2048 uint4)
    {
        const uint4* src = reinterpret_cast<const uint4*>(w1t);
        #pragma unroll
        for (int i = tid; i < 2048; i += 256)
            *reinterpret_cast<uint4*>(&lds_w[i >> 4][(i & 15) * 8]) = src[i];
    }
    __syncthreads();

    const int lane = tid & 63, wv = tid >> 6;
    const int la = lane & 15, kg = lane >> 4;

    f32x4 acc[2][8] = {};
    #pragma unroll
    for (int kk = 0; kk < 4; ++kk) {
        const int kbase = kk * 32 + kg * 8;
        bf16x8 a[2], b[8];
        #pragma unroll
        for (int m = 0; m < 2; ++m)
            a[m] = *reinterpret_cast<const bf16x8*>(&lds_msg[wv * 32 + m * 16 + la][kbase]);
        #pragma unroll
        for (int n = 0; n < 8; ++n)
            b[n] = *reinterpret_cast<const bf16x8*>(&lds_w[n * 16 + la][kbase]);
        #pragma unroll
        for (int m = 0; m < 2; ++m)
            #pragma unroll
            for (int n = 0; n < 8; ++n)
                acc[m][n] = __builtin_amdgcn_mfma_f32_16x16x32_bf16(a[m], b[n], acc[m][n], 0, 0, 0);
    }

    // layer 2: logit[row] = sum_col relu(acc+b1[col]) * w2[col] + b2
    const float b2v = b2[0];
    float part[2][4] = {};
    #pragma unroll
    for (int n = 0; n < 8; ++n) {
        const float w2v = w2[n * 16 + la];
        const float b1v = b1[n * 16 + la];
        #pragma unroll
        for (int m = 0; m < 2; ++m)
            #pragma unroll
            for (int i = 0; i < 4; ++i)
                part[m][i] += fmaxf(acc[m][n][i] + b1v, 0.f) * w2v;
    }
    #pragma unroll
    for (int s = 1; s < 16; s <<= 1)
        #pragma unroll
        for (int m = 0; m < 2; ++m)
            #pragma unroll
            for (int i = 0; i < 4; ++i)
                part[m][i] += __shfl_xor(part[m][i], s, 64);
    if (la == 0) {
        #pragma unroll
        for (int m = 0; m < 2; ++m)
            #pragma unroll
            for (int i = 0; i < 4; ++i) {
                const int row = wv * 32 + m * 16 + kg * 4 + i;
                const int ge = e0 + row;
                if (ge < E) {
                    const float lg = part[m][i] + b2v;
                    logit_out[ge] = lg;
                    atomicMax(&gmax[selfi[ge]], fkey(lg));
                }
            }
    }
}

__global__ void k_softexp(const float* __restrict__ logit,
                          const int* __restrict__ selfi, const int* __restrict__ nbri,
                          const float* __restrict__ nodew, const float* __restrict__ powp,
                          const unsigned* __restrict__ gmax, float* __restrict__ gate_e,
                          float* __restrict__ gsum, int E)
{
    int e = blockIdx.x * 256 + threadIdx.x;
    if (e >= E) return;
    const float p = powp[0];
    const int s = selfi[e];
    const float m = funkey(gmax[s]);
    const float g = powf(nodew[nbri[e]], p) * expf(logit[e] - m);
    gate_e[e] = g;
    unsafeAtomicAdd(&gsum[s], g);
}

__global__ void __launch_bounds__(256, 2)
k_message(const __bf16* __restrict__ feat,
          const int* __restrict__ selfi, const int* __restrict__ nbri,
          const __bf16* __restrict__ w1t, const float* __restrict__ b1,
          const __bf16* __restrict__ w2t, const float* __restrict__ b2,
          const float* __restrict__ gate_e, const float* __restrict__ gsum,
          float* __restrict__ out, int E)
{
    __shared__ __align__(16) __bf16 lds_msg[BE][LSTR];
    __shared__ __align__(16) __bf16 lds_w[HID][LSTR];
    const int tid = threadIdx.x;
    const int e0 = blockIdx.x * BE;

    {
        const int edge = tid >> 1, half = tid & 1;
        const int ge = e0 + edge;
        int node = 0;
        if (ge < E) node = half ? nbri[ge] : selfi[ge];
        const uint4* src = reinterpret_cast<const uint4*>(feat + (size_t)node * D_FEAT);
        uint4* dst = reinterpret_cast<uint4*>(&lds_msg[edge][half * 64]);
        #pragma unroll
        for (int j = 0; j < 8; ++j) dst[j] = src[j];
    }
    {
        const uint4* src = reinterpret_cast<const uint4*>(w1t);
        #pragma unroll
        for (int i = tid; i < 2048; i += 256)
            *reinterpret_cast<uint4*>(&lds_w[i >> 4][(i & 15) * 8]) = src[i];
    }
    __syncthreads();

    const int lane = tid & 63, wv = tid >> 6;
    const int la = lane & 15, kg = lane >> 4;

    f32x4 acc[2][8] = {};
    #pragma unroll
    for (int kk = 0; kk < 4; ++kk) {
        const int kbase = kk * 32 + kg * 8;
        bf16x8 a[2], b[8];
        #pragma unroll
        for (int m = 0; m < 2; ++m)
            a[m] = *reinterpret_cast<const bf16x8*>(&lds_msg[wv * 32 + m * 16 + la][kbase]);
        #pragma unroll
        for (int n = 0; n < 8; ++n)
            b[n] = *reinterpret_cast<const bf16x8*>(&lds_w[n * 16 + la][kbase]);
        #pragma unroll
        for (int m = 0; m < 2; ++m)
            #pragma unroll
            for (int n = 0; n < 8; ++n)
                acc[m][n] = __builtin_amdgcn_mfma_f32_16x16x32_bf16(a[m], b[n], acc[m][n], 0, 0, 0);
    }
    __syncthreads();  // done reading lds_msg (A) and lds_w (mw1t)

    // h = relu(acc + b1) -> bf16 back into lds_msg; stage mw2t into lds_w rows 0..63
    {
        const uint4* src = reinterpret_cast<const uint4*>(w2t);
        #pragma unroll
        for (int i = tid; i < 1024; i += 256)
            *reinterpret_cast<uint4*>(&lds_w[i >> 4][(i & 15) * 8]) = src[i];
    }
    #pragma unroll
    for (int n = 0; n < 8; ++n) {
        const float b1v = b1[n * 16 + la];
        #pragma unroll
        for (int m = 0; m < 2; ++m)
            #pragma unroll
            for (int i = 0; i < 4; ++i) {
                const float h = fmaxf(acc[m][n][i] + b1v, 0.f);
                lds_msg[wv * 32 + m * 16 + kg * 4 + i][n * 16 + la] = (__bf16)h;
            }
    }
    __syncthreads();

    // GEMM2: x[128 x 64] = h @ mw2, K=128
    f32x4 acc2[2][4] = {};
    #pragma unroll
    for (int kk = 0; kk < 4; ++kk) {
        const int kbase = kk * 32 + kg * 8;
        bf16x8 a[2], b[4];
        #pragma unroll
        for (int m = 0; m < 2; ++m)
            a[m] = *reinterpret_cast<const bf16x8*>(&lds_msg[wv * 32 + m * 16 + la][kbase]);
        #pragma unroll
        for (int n = 0; n < 4; ++n)
            b[n] = *reinterpret_cast<const bf16x8*>(&lds_w[n * 16 + la][kbase]);
        #pragma unroll
        for (int m = 0; m < 2; ++m)
            #pragma unroll
            for (int n = 0; n < 4; ++n)
                acc2[m][n] = __builtin_amdgcn_mfma_f32_16x16x32_bf16(a[m], b[n], acc2[m][n], 0, 0, 0);
    }

    // epilogue: coef * (x + b2) scattered to out[self][col]
    float coef[2][4];
    int snode[2][4];
    #pragma unroll
    for (int m = 0; m < 2; ++m)
        #pragma unroll
        for (int i = 0; i < 4; ++i) {
            const int ge = e0 + wv * 32 + m * 16 + kg * 4 + i;
            float c = 0.f; int sn = 0;
            if (ge < E) {
                sn = selfi[ge];
                c = gate_e[ge] / (gsum[sn] + 1e-10f);
            }
            coef[m][i] = c; snode[m][i] = sn;
        }
    #pragma unroll
    for (int n = 0; n < 4; ++n) {
        const float b2v = b2[n * 16 + la];
        #pragma unroll
        for (int m = 0; m < 2; ++m)
            #pragma unroll
            for (int i = 0; i < 4; ++i) {
                const int ge = e0 + wv * 32 + m * 16 + kg * 4 + i;
                if (ge < E) {
                    const float val = coef[m][i] * (acc2[m][n][i] + b2v);
                    unsafeAtomicAdd(&out[(size_t)snode[m][i] * D_FEAT + n * 16 + la], val);
                }
            }
    }
}

extern "C" void kernel_launch(void* const* d_in, const int* in_sizes, int n_in,
                              void* d_out, int out_size, void* d_ws, size_t ws_size,
                              hipStream_t stream)
{
    const float* node_w = (const float*)d_in[0];
    const float* prev   = (const float*)d_in[1];
    const int*   selfi  = (const int*)d_in[2];
    const int*   nbri   = (const int*)d_in[3];
    const float* gw1 = (const float*)d_in[4];
    const float* gb1 = (const float*)d_in[5];
    const float* gw2 = (const float*)d_in[6];
    const float* gb2 = (const float*)d_in[7];
    const float* mw1 = (const float*)d_in[8];
    const float* mb1 = (const float*)d_in[9];
    const float* mw2 = (const float*)d_in[10];
    const float* mb2 = (const float*)d_in[11];
    const float* powp = (const float*)d_in[12];
    const int N = in_sizes[0];
    const int E = in_sizes[2];
    float* out = (float*)d_out;

    char* ws = (char*)d_ws;
    size_t off = 0;
    auto alloc = [&](size_t bytes) {
        void* p = ws + off;
        off = (off + bytes + 255) & ~(size_t)255;
        return p;
    };
    __bf16* featb  = (__bf16*)alloc((size_t)N * D_FEAT * 2);
    __bf16* gw1t   = (__bf16*)alloc(128 * 128 * 2);
    __bf16* mw1t   = (__bf16*)alloc(128 * 128 * 2);
    __bf16* mw2t   = (__bf16*)alloc(64 * 128 * 2);
    float* logit   = (float*)alloc((size_t)E * 4);
    float* gate_e  = (float*)alloc((size_t)E * 4);
    unsigned* gmax = (unsigned*)alloc((size_t)N * 4);
    float* gsum    = (float*)alloc((size_t)N * 4);

    const int totalF = N * D_FEAT;
    k_init<<<(totalF + 255) / 256, 256, 0, stream>>>(prev, out, featb, gmax, gsum, totalF, N);
    k_wconv<<<(40960 + 255) / 256, 256, 0, stream>>>(gw1, mw1, mw2, gw1t, mw1t, mw2t);
    k_gate<<<(E + BE - 1) / BE, 256, 0, stream>>>(featb, selfi, nbri, gw1t, gb1, gw2, gb2, logit, gmax, E);
    k_softexp<<<(E + 255) / 256, 256, 0, stream>>>(logit, selfi, nbri, node_w, powp, gmax, gate_e, gsum, E);
    k_message<<<(E + BE - 1) / BE, 256, 0, stream>>>(featb, selfi, nbri, mw1t, mb1, mw2t, mb2, gate_e, gsum, out, E);
}

// Round 2
// 884.995 us; speedup vs baseline: 1.0054x; 1.0054x over previous
//
#include <hip/hip_runtime.h>
#include <hip/hip_bf16.h>

typedef __bf16 bf16x8 __attribute__((ext_vector_type(8)));
typedef float f32x4 __attribute__((ext_vector_type(4)));

#define D_FEAT 64
#define HID 128
#define BE 128
#define LSTR 136   // bf16 row stride: 272B, 16B-aligned, 2-way bank alias (free)
#define SCAN_BLK 1024

static __device__ __forceinline__ unsigned fkey(float f) {
    unsigned u = __float_as_uint(f);
    return (u & 0x80000000u) ? ~u : (u | 0x80000000u);
}
static __device__ __forceinline__ float funkey(unsigned k) {
    unsigned u = (k & 0x80000000u) ? (k & 0x7fffffffu) : ~k;
    return __uint_as_float(u);
}

__global__ void k_init(const float* __restrict__ prev, float* __restrict__ out,
                       __bf16* __restrict__ featb, unsigned* __restrict__ gmax,
                       float* __restrict__ gsum, int* __restrict__ hist,
                       int total, int N)
{
    int i = blockIdx.x * 256 + threadIdx.x;
    if (i < total) {
        float v = prev[i];
        out[i] = v;
        featb[i] = (__bf16)v;
    }
    if (i < N) { gmax[i] = 0u; gsum[i] = 0.f; hist[i] = 0; }
}

__global__ void k_wconv(const float* __restrict__ gw1, const float* __restrict__ mw1,
                        const float* __restrict__ mw2,
                        __bf16* __restrict__ gw1t, __bf16* __restrict__ mw1t,
                        __bf16* __restrict__ mw2t)
{
    int i = blockIdx.x * 256 + threadIdx.x;
    if (i < 16384) {
        int c = i >> 7, k = i & 127;
        gw1t[i] = (__bf16)gw1[k * 128 + c];
    } else if (i < 32768) {
        int j = i - 16384; int c = j >> 7, k = j & 127;
        mw1t[j] = (__bf16)mw1[k * 128 + c];
    } else if (i < 40960) {
        int j = i - 32768; int c = j >> 7, k = j & 127;
        mw2t[j] = (__bf16)mw2[k * 64 + c];
    }
}

// ---- counting sort by self_idx ----
__global__ void k_hist(const int* __restrict__ selfi, int* __restrict__ hist, int E)
{
    int e = blockIdx.x * 256 + threadIdx.x;
    if (e < E) atomicAdd(&hist[selfi[e]], 1);
}

__global__ void k_scan1(const int* __restrict__ hist, int* __restrict__ incl,
                        int* __restrict__ bsum, int N)
{
    __shared__ int sd[SCAN_BLK];
    int i = blockIdx.x * SCAN_BLK + threadIdx.x;
    int v = (i < N) ? hist[i] : 0;
    sd[threadIdx.x] = v;
    __syncthreads();
    #pragma unroll
    for (int off = 1; off < SCAN_BLK; off <<= 1) {
        int t = (threadIdx.x >= off) ? sd[threadIdx.x - off] : 0;
        __syncthreads();
        sd[threadIdx.x] += t;
        __syncthreads();
    }
    if (i < N) incl[i] = sd[threadIdx.x];
    if (threadIdx.x == SCAN_BLK - 1) bsum[blockIdx.x] = sd[SCAN_BLK - 1];
}

__global__ void k_scan2(int* __restrict__ bsum, int* __restrict__ boff, int nb)
{
    if (threadIdx.x == 0 && blockIdx.x == 0) {
        int run = 0;
        for (int j = 0; j < nb; ++j) { boff[j] = run; run += bsum[j]; }
    }
}

__global__ void k_scan3(const int* __restrict__ incl, const int* __restrict__ hist,
                        const int* __restrict__ boff, int* __restrict__ cursor, int N)
{
    int i = blockIdx.x * SCAN_BLK + threadIdx.x;
    if (i < N) cursor[i] = incl[i] - hist[i] + boff[blockIdx.x];
}

__global__ void k_scatter(const int* __restrict__ selfi, const int* __restrict__ nbri,
                          int* __restrict__ cursor, int* __restrict__ self_p,
                          int* __restrict__ nbr_p, int E)
{
    int e = blockIdx.x * 256 + threadIdx.x;
    if (e >= E) return;
    int s = selfi[e];
    int pos = atomicAdd(&cursor[s], 1);
    self_p[pos] = s;
    nbr_p[pos] = nbri[e];
}

// ---- gate logits: GEMM1 (MFMA) + dot; edges in sorted order ----
// NOTE: rows are partitioned per-wave (wave wv owns rows [wv*32, wv*32+32)),
// so every LDS access is wave-local -> no __syncthreads needed anywhere.
__global__ void __launch_bounds__(256, 4)
k_gate(const __bf16* __restrict__ feat,
       const int* __restrict__ self_p, const int* __restrict__ nbr_p,
       const __bf16* __restrict__ w1t, const float* __restrict__ b1,
       const float* __restrict__ w2, const float* __restrict__ b2,
       float* __restrict__ logit_p, unsigned* __restrict__ gmax, int E)
{
    __shared__ __align__(16) __bf16 lds_msg[BE][LSTR];
    __shared__ int selfs[BE];
    __shared__ float logit_s[BE];
    const int tid = threadIdx.x;
    const int e0 = blockIdx.x * BE;

    {
        const int edge = tid >> 1, half = tid & 1, ge = e0 + edge;
        int node = 0;
        if (ge < E) node = half ? nbr_p[ge] : self_p[ge];
        if (!half) selfs[edge] = (ge < E) ? node : -1;
        const uint4* src = reinterpret_cast<const uint4*>(feat + (size_t)node * D_FEAT);
        uint4* dst = reinterpret_cast<uint4*>(&lds_msg[edge][half * 64]);
        #pragma unroll
        for (int j = 0; j < 8; ++j) dst[j] = src[j];
    }

    const int lane = tid & 63, wv = tid >> 6;
    const int la = lane & 15, kg = lane >> 4;

    f32x4 acc[2][8] = {};
    #pragma unroll
    for (int kk = 0; kk < 4; ++kk) {
        const int kbase = kk * 32 + kg * 8;
        bf16x8 a[2];
        #pragma unroll
        for (int m = 0; m < 2; ++m)
            a[m] = *reinterpret_cast<const bf16x8*>(&lds_msg[wv * 32 + m * 16 + la][kbase]);
        #pragma unroll
        for (int n = 0; n < 8; ++n) {
            bf16x8 b = *reinterpret_cast<const bf16x8*>(w1t + (size_t)(n * 16 + la) * HID + kbase);
            #pragma unroll
            for (int m = 0; m < 2; ++m)
                acc[m][n] = __builtin_amdgcn_mfma_f32_16x16x32_bf16(a[m], b, acc[m][n], 0, 0, 0);
        }
    }

    const float b2v = b2[0];
    float part[2][4] = {};
    #pragma unroll
    for (int n = 0; n < 8; ++n) {
        const float w2v = w2[n * 16 + la];
        const float b1v = b1[n * 16 + la];
        #pragma unroll
        for (int m = 0; m < 2; ++m)
            #pragma unroll
            for (int i = 0; i < 4; ++i)
                part[m][i] += fmaxf(acc[m][n][i] + b1v, 0.f) * w2v;
    }
    #pragma unroll
    for (int s = 1; s < 16; s <<= 1)
        #pragma unroll
        for (int m = 0; m < 2; ++m)
            #pragma unroll
            for (int i = 0; i < 4; ++i)
                part[m][i] += __shfl_xor(part[m][i], s, 64);

    if (la == 0) {
        #pragma unroll
        for (int m = 0; m < 2; ++m)
            #pragma unroll
            for (int i = 0; i < 4; ++i) {
                const int row = wv * 32 + m * 16 + kg * 4 + i;
                const int ge = e0 + row;
                if (ge < E) {
                    const float lg = part[m][i] + b2v;
                    logit_p[ge] = lg;
                    logit_s[row] = lg;
                }
            }
    }
    // wave-local segmented max -> one atomicMax per segment
    if (lane == 0) {
        const int r0 = wv * 32;
        int cur = selfs[r0];
        float mx = -3.4e38f;
        for (int r = 0; r < 32; ++r) {
            int s = selfs[r0 + r];
            if (s != cur) {
                if (cur >= 0) atomicMax(&gmax[cur], fkey(mx));
                mx = -3.4e38f; cur = s;
            }
            mx = fmaxf(mx, logit_s[r0 + r]);
        }
        if (cur >= 0) atomicMax(&gmax[cur], fkey(mx));
    }
}

// ---- softmax numerator + segmented denominator sum ----
__global__ void k_softexp(const float* __restrict__ logit_p,
                          const int* __restrict__ self_p, const int* __restrict__ nbr_p,
                          const float* __restrict__ nodew, const float* __restrict__ powp,
                          const unsigned* __restrict__ gmax, float* __restrict__ gate_p,
                          float* __restrict__ gsum, int E)
{
    int base = (blockIdx.x * 256 + threadIdx.x) * 8;
    if (base >= E) return;
    const float p = powp[0];
    int4 sa = *reinterpret_cast<const int4*>(self_p + base);
    int4 sb = *reinterpret_cast<const int4*>(self_p + base + 4);
    int4 na = *reinterpret_cast<const int4*>(nbr_p + base);
    int4 nb = *reinterpret_cast<const int4*>(nbr_p + base + 4);
    float4 la = *reinterpret_cast<const float4*>(logit_p + base);
    float4 lb = *reinterpret_cast<const float4*>(logit_p + base + 4);
    int ss[8] = {sa.x, sa.y, sa.z, sa.w, sb.x, sb.y, sb.z, sb.w};
    int nn[8] = {na.x, na.y, na.z, na.w, nb.x, nb.y, nb.z, nb.w};
    float lg[8] = {la.x, la.y, la.z, la.w, lb.x, lb.y, lb.z, lb.w};
    float g[8];
    #pragma unroll
    for (int j = 0; j < 8; ++j)
        g[j] = powf(nodew[nn[j]], p) * __expf(lg[j] - funkey(gmax[ss[j]]));
    float4 ga = {g[0], g[1], g[2], g[3]};
    float4 gb = {g[4], g[5], g[6], g[7]};
    *reinterpret_cast<float4*>(gate_p + base) = ga;
    *reinterpret_cast<float4*>(gate_p + base + 4) = gb;
    // segmented flush
    float acc = g[0]; int cur = ss[0];
    #pragma unroll
    for (int j = 1; j < 8; ++j) {
        if (ss[j] != cur) { unsafeAtomicAdd(&gsum[cur], acc); acc = 0.f; cur = ss[j]; }
        acc += g[j];
    }
    unsafeAtomicAdd(&gsum[cur], acc);
}

// ---- message MLP + gated segmented scatter ----
__global__ void __launch_bounds__(256, 4)
k_message(const __bf16* __restrict__ feat,
          const int* __restrict__ self_p, const int* __restrict__ nbr_p,
          const __bf16* __restrict__ w1t, const float* __restrict__ b1,
          const __bf16* __restrict__ w2t, const float* __restrict__ b2,
          const float* __restrict__ gate_p, const float* __restrict__ gsum,
          float* __restrict__ out, int E)
{
    __shared__ __align__(16) __bf16 lds_msg[BE][LSTR];
    __shared__ int selfs[BE];
    const int tid = threadIdx.x;
    const int e0 = blockIdx.x * BE;

    {
        const int edge = tid >> 1, half = tid & 1, ge = e0 + edge;
        int node = 0;
        if (ge < E) node = half ? nbr_p[ge] : self_p[ge];
        if (!half) selfs[edge] = (ge < E) ? node : -1;
        const uint4* src = reinterpret_cast<const uint4*>(feat + (size_t)node * D_FEAT);
        uint4* dst = reinterpret_cast<uint4*>(&lds_msg[edge][half * 64]);
        #pragma unroll
        for (int j = 0; j < 8; ++j) dst[j] = src[j];
    }

    const int lane = tid & 63, wv = tid >> 6;
    const int la = lane & 15, kg = lane >> 4;

    f32x4 acc[2][8] = {};
    #pragma unroll
    for (int kk = 0; kk < 4; ++kk) {
        const int kbase = kk * 32 + kg * 8;
        bf16x8 a[2];
        #pragma unroll
        for (int m = 0; m < 2; ++m)
            a[m] = *reinterpret_cast<const bf16x8*>(&lds_msg[wv * 32 + m * 16 + la][kbase]);
        #pragma unroll
        for (int n = 0; n < 8; ++n) {
            bf16x8 b = *reinterpret_cast<const bf16x8*>(w1t + (size_t)(n * 16 + la) * HID + kbase);
            #pragma unroll
            for (int m = 0; m < 2; ++m)
                acc[m][n] = __builtin_amdgcn_mfma_f32_16x16x32_bf16(a[m], b, acc[m][n], 0, 0, 0);
        }
    }

    // h = relu(acc+b1) -> bf16, overwrite own rows of lds_msg
    #pragma unroll
    for (int n = 0; n < 8; ++n) {
        const float b1v = b1[n * 16 + la];
        #pragma unroll
        for (int m = 0; m < 2; ++m)
            #pragma unroll
            for (int i = 0; i < 4; ++i)
                lds_msg[wv * 32 + m * 16 + kg * 4 + i][n * 16 + la] =
                    (__bf16)fmaxf(acc[m][n][i] + b1v, 0.f);
    }

    // GEMM2: x = h @ mw2  (K=128, 64 cols), B direct from global
    f32x4 acc2[2][4] = {};
    #pragma unroll
    for (int kk = 0; kk < 4; ++kk) {
        const int kbase = kk * 32 + kg * 8;
        bf16x8 a[2];
        #pragma unroll
        for (int m = 0; m < 2; ++m)
            a[m] = *reinterpret_cast<const bf16x8*>(&lds_msg[wv * 32 + m * 16 + la][kbase]);
        #pragma unroll
        for (int n = 0; n < 4; ++n) {
            bf16x8 b = *reinterpret_cast<const bf16x8*>(w2t + (size_t)(n * 16 + la) * HID + kbase);
            #pragma unroll
            for (int m = 0; m < 2; ++m)
                acc2[m][n] = __builtin_amdgcn_mfma_f32_16x16x32_bf16(a[m], b, acc2[m][n], 0, 0, 0);
        }
    }

    // coef per own row
    float coef[2][4];
    #pragma unroll
    for (int m = 0; m < 2; ++m)
        #pragma unroll
        for (int i = 0; i < 4; ++i) {
            const int row = wv * 32 + m * 16 + kg * 4 + i;
            const int ge = e0 + row;
            float c = 0.f;
            if (ge < E) {
                const int sn = selfs[row];
                c = gate_p[ge] / (gsum[sn] + 1e-10f);
            }
            coef[m][i] = c;
        }

    // write gated message into f32 xbuf (reuse lds_msg storage, own rows only)
    float (*xb)[68] = reinterpret_cast<float(*)[68]>(&lds_msg[0][0]);
    #pragma unroll
    for (int n = 0; n < 4; ++n) {
        const float b2v = b2[n * 16 + la];
        #pragma unroll
        for (int m = 0; m < 2; ++m)
            #pragma unroll
            for (int i = 0; i < 4; ++i) {
                const int row = wv * 32 + m * 16 + kg * 4 + i;
                xb[row][n * 16 + la] = coef[m][i] * (acc2[m][n][i] + b2v);
            }
    }

    // wave-local segmented column sum -> one 64-lane atomic row per segment
    {
        const int r0 = wv * 32;
        float accv = 0.f;
        int cur = selfs[r0];
        for (int r = 0; r < 32; ++r) {
            int s = selfs[r0 + r];
            if (s != cur) {
                if (cur >= 0) unsafeAtomicAdd(&out[(size_t)cur * D_FEAT + lane], accv);
                accv = 0.f; cur = s;
            }
            accv += xb[r0 + r][lane];
        }
        if (cur >= 0) unsafeAtomicAdd(&out[(size_t)cur * D_FEAT + lane], accv);
    }
}

extern "C" void kernel_launch(void* const* d_in, const int* in_sizes, int n_in,
                              void* d_out, int out_size, void* d_ws, size_t ws_size,
                              hipStream_t stream)
{
    const float* node_w = (const float*)d_in[0];
    const float* prev   = (const float*)d_in[1];
    const int*   selfi  = (const int*)d_in[2];
    const int*   nbri   = (const int*)d_in[3];
    const float* gw1 = (const float*)d_in[4];
    const float* gb1 = (const float*)d_in[5];
    const float* gw2 = (const float*)d_in[6];
    const float* gb2 = (const float*)d_in[7];
    const float* mw1 = (const float*)d_in[8];
    const float* mb1 = (const float*)d_in[9];
    const float* mw2 = (const float*)d_in[10];
    const float* mb2 = (const float*)d_in[11];
    const float* powp = (const float*)d_in[12];
    const int N = in_sizes[0];
    const int E = in_sizes[2];
    float* out = (float*)d_out;

    char* ws = (char*)d_ws;
    size_t off = 0;
    auto alloc = [&](size_t bytes) {
        void* p = ws + off;
        off = (off + bytes + 255) & ~(size_t)255;
        return p;
    };
    __bf16* featb  = (__bf16*)alloc((size_t)N * D_FEAT * 2);
    __bf16* gw1t   = (__bf16*)alloc(128 * 128 * 2);
    __bf16* mw1t   = (__bf16*)alloc(128 * 128 * 2);
    __bf16* mw2t   = (__bf16*)alloc(64 * 128 * 2);
    float* logit_p = (float*)alloc((size_t)E * 4);
    float* gate_p  = (float*)alloc((size_t)E * 4);
    int* self_p    = (int*)alloc((size_t)E * 4);
    int* nbr_p     = (int*)alloc((size_t)E * 4);
    unsigned* gmax = (unsigned*)alloc((size_t)N * 4);
    float* gsum    = (float*)alloc((size_t)N * 4);
    int* hist      = (int*)alloc((size_t)N * 4);
    int* cursor    = (int*)alloc((size_t)N * 4);
    int* incl      = (int*)alloc((size_t)N * 4);
    const int nb = (N + SCAN_BLK - 1) / SCAN_BLK;
    int* bsum      = (int*)alloc((size_t)nb * 4);
    int* boff      = (int*)alloc((size_t)nb * 4);

    const int totalF = N * D_FEAT;
    k_init<<<(totalF + 255) / 256, 256, 0, stream>>>(prev, out, featb, gmax, gsum, hist, totalF, N);
    k_wconv<<<(40960 + 255) / 256, 256, 0, stream>>>(gw1, mw1, mw2, gw1t, mw1t, mw2t);
    k_hist<<<(E + 255) / 256, 256, 0, stream>>>(selfi, hist, E);
    k_scan1<<<nb, SCAN_BLK, 0, stream>>>(hist, incl, bsum, N);
    k_scan2<<<1, 64, 0, stream>>>(bsum, boff, nb);
    k_scan3<<<nb, SCAN_BLK, 0, stream>>>(incl, hist, boff, cursor, N);
    k_scatter<<<(E + 255) / 256, 256, 0, stream>>>(selfi, nbri, cursor, self_p, nbr_p, E);
    k_gate<<<(E + BE - 1) / BE, 256, 0, stream>>>(featb, self_p, nbr_p, gw1t, gb1, gw2, gb2, logit_p, gmax, E);
    k_softexp<<<(E / 8 + 255) / 256, 256, 0, stream>>>(logit_p, self_p, nbr_p, node_w, powp, gmax, gate_p, gsum, E);
    k_message<<<(E + BE - 1) / BE, 256, 0, stream>>>(featb, self_p, nbr_p, mw1t, mb1, mw2t, mb2, gate_p, gsum, out, E);
}

// Round 3
// 851.560 us; speedup vs baseline: 1.0449x; 1.0393x over previous
//
#include <hip/hip_runtime.h>
#include <hip/hip_bf16.h>

typedef __bf16 bf16x8 __attribute__((ext_vector_type(8)));
typedef float f32x4 __attribute__((ext_vector_type(4)));

#define D_FEAT 64
#define HID 128
#define WIN 128          // edge window per block (segment starts)
#define TILE 192         // max edges per block = WIN-1 + maxdeg(<=64)
#define LSTR 136         // bf16 row stride: 272B, 16B-aligned
#define SCAN_BLK 1024

__global__ void k_init(const float* __restrict__ prev, float* __restrict__ out,
                       __bf16* __restrict__ featb, int* __restrict__ hist,
                       int* __restrict__ s_lo, int* __restrict__ s_hi,
                       int total, int N, int NB)
{
    int i = blockIdx.x * 256 + threadIdx.x;
    if (i < total) {
        float v = prev[i];
        out[i] = v;
        featb[i] = (__bf16)v;
    }
    if (i < N) hist[i] = 0;
    if (i < NB) { s_lo[i] = 0x7fffffff; s_hi[i] = 0; }
}

__global__ void k_wconv(const float* __restrict__ gw1, const float* __restrict__ mw1,
                        const float* __restrict__ mw2,
                        __bf16* __restrict__ gw1t, __bf16* __restrict__ mw1t,
                        __bf16* __restrict__ mw2t)
{
    int i = blockIdx.x * 256 + threadIdx.x;
    if (i < 16384) {
        int c = i >> 7, k = i & 127;
        gw1t[i] = (__bf16)gw1[k * 128 + c];
    } else if (i < 32768) {
        int j = i - 16384; int c = j >> 7, k = j & 127;
        mw1t[j] = (__bf16)mw1[k * 128 + c];
    } else if (i < 40960) {
        int j = i - 32768; int c = j >> 7, k = j & 127;
        mw2t[j] = (__bf16)mw2[k * 64 + c];
    }
}

// ---- counting sort by self_idx ----
__global__ void k_hist(const int* __restrict__ selfi, int* __restrict__ hist, int E)
{
    int e = blockIdx.x * 256 + threadIdx.x;
    if (e < E) atomicAdd(&hist[selfi[e]], 1);
}

__global__ void k_scan1(const int* __restrict__ hist, int* __restrict__ incl,
                        int* __restrict__ bsum, int N)
{
    __shared__ int sd[SCAN_BLK];
    int i = blockIdx.x * SCAN_BLK + threadIdx.x;
    int v = (i < N) ? hist[i] : 0;
    sd[threadIdx.x] = v;
    __syncthreads();
    #pragma unroll
    for (int off = 1; off < SCAN_BLK; off <<= 1) {
        int t = (threadIdx.x >= off) ? sd[threadIdx.x - off] : 0;
        __syncthreads();
        sd[threadIdx.x] += t;
        __syncthreads();
    }
    if (i < N) incl[i] = sd[threadIdx.x];
    if (threadIdx.x == SCAN_BLK - 1) bsum[blockIdx.x] = sd[SCAN_BLK - 1];
}

__global__ void k_scan2(int* __restrict__ bsum, int* __restrict__ boff, int nb)
{
    if (threadIdx.x == 0 && blockIdx.x == 0) {
        int run = 0;
        for (int j = 0; j < nb; ++j) { boff[j] = run; run += bsum[j]; }
    }
}

// exclusive scan -> starts[] (immutable) and cursor[] (scatter-mutable)
__global__ void k_scan3(const int* __restrict__ incl, const int* __restrict__ hist,
                        const int* __restrict__ boff, int* __restrict__ cursor,
                        int* __restrict__ starts, int N)
{
    int i = blockIdx.x * SCAN_BLK + threadIdx.x;
    if (i < N) {
        int v = incl[i] - hist[i] + boff[blockIdx.x];
        cursor[i] = v;
        starts[i] = v;
    }
}

__global__ void k_scatter(const int* __restrict__ selfi, const int* __restrict__ nbri,
                          int* __restrict__ cursor, int* __restrict__ self_p,
                          int* __restrict__ nbr_p, int E)
{
    int e = blockIdx.x * 256 + threadIdx.x;
    if (e >= E) return;
    int s = selfi[e];
    int pos = atomicAdd(&cursor[s], 1);
    self_p[pos] = s;
    nbr_p[pos] = nbri[e];
}

// assign each non-empty segment to the block owning its start window
__global__ void k_blockmeta(const int* __restrict__ starts, int* __restrict__ s_lo,
                            int* __restrict__ s_hi, int N, int E)
{
    int s = blockIdx.x * 256 + threadIdx.x;
    if (s >= N) return;
    int st = starts[s];
    int en = (s + 1 < N) ? starts[s + 1] : E;
    if (en <= st) return;          // zero-degree node: no edges
    int b = st >> 7;               // WIN = 128
    atomicMin(&s_lo[b], s);
    atomicMax(&s_hi[b], s + 1);
}

// ---- the fused kernel: gather -> gate MLP -> block-local segment softmax
//      -> msg MLP -> gated segment sum -> non-atomic store ----
__global__ void __launch_bounds__(256, 3)
k_fused(const __bf16* __restrict__ feat,
        const int* __restrict__ self_p, const int* __restrict__ nbr_p,
        const int* __restrict__ starts,
        const int* __restrict__ s_lo, const int* __restrict__ s_hi,
        const float* __restrict__ nodew, const float* __restrict__ powp,
        const __bf16* __restrict__ gw1t, const float* __restrict__ gb1,
        const float* __restrict__ gw2, const float* __restrict__ gb2,
        const __bf16* __restrict__ mw1t, const float* __restrict__ mb1,
        const __bf16* __restrict__ mw2t, const float* __restrict__ mb2,
        const float* __restrict__ prev, float* __restrict__ out,
        int N, int E)
{
    __shared__ __align__(16) __bf16 msg[TILE][LSTR];  // reused: h (bf16), then xb (f32 [TILE][68])
    __shared__ float logit_s[TILE];                   // reused as coef after softmax
    __shared__ int nbr_s[TILE];

    const int b = blockIdx.x;
    const int s0 = s_lo[b];
    if (s0 == 0x7fffffff) return;
    const int s1 = s_hi[b];
    const int e0 = starts[s0];
    const int e1 = (s1 < N) ? starts[s1] : E;
    int ne = e1 - e0;
    if (ne > TILE) ne = TILE;   // unreachable for this degree distribution; safety

    const int tid = threadIdx.x;

    // ---- stage msg tile: row r = [self(64) | nbr(64)] bf16 ----
    {
        const int pr = tid >> 1, half = tid & 1;
        for (int r = pr; r < ne; r += 128) {
            const int ge = e0 + r;
            const int node = half ? nbr_p[ge] : self_p[ge];
            if (half) nbr_s[r] = node;
            const uint4* src = reinterpret_cast<const uint4*>(feat + (size_t)node * D_FEAT);
            uint4* dst = reinterpret_cast<uint4*>(&msg[r][half * 64]);
            #pragma unroll
            for (int j = 0; j < 8; ++j) dst[j] = src[j];
        }
    }
    __syncthreads();

    const int lane = tid & 63, wv = tid >> 6;
    const int la = lane & 15, kg = lane >> 4;
    // wave wv owns 16-row m-tiles {wv, wv+4, wv+8} (interleaved for load balance)
    const int row0[3] = {wv * 16, wv * 16 + 64, wv * 16 + 128};
    bool live[3];
    #pragma unroll
    for (int m = 0; m < 3; ++m) live[m] = (row0[m] < ne);

    // ---- GEMM1 gate: acc = msg @ gw1 ----
    f32x4 acc[3][8] = {};
    #pragma unroll
    for (int kk = 0; kk < 4; ++kk) {
        const int kbase = kk * 32 + kg * 8;
        bf16x8 a[3];
        #pragma unroll
        for (int m = 0; m < 3; ++m)
            if (live[m]) a[m] = *reinterpret_cast<const bf16x8*>(&msg[row0[m] + la][kbase]);
        #pragma unroll
        for (int n = 0; n < 8; ++n) {
            bf16x8 bb = *reinterpret_cast<const bf16x8*>(gw1t + (size_t)(n * 16 + la) * HID + kbase);
            #pragma unroll
            for (int m = 0; m < 3; ++m)
                if (live[m]) acc[m][n] = __builtin_amdgcn_mfma_f32_16x16x32_bf16(a[m], bb, acc[m][n], 0, 0, 0);
        }
    }

    // ---- gate layer 2: logit = relu(acc+gb1) . gw2 + gb2 ----
    {
        const float b2v = gb2[0];
        float part[3][4] = {};
        #pragma unroll
        for (int n = 0; n < 8; ++n) {
            const float w2v = gw2[n * 16 + la];
            const float b1v = gb1[n * 16 + la];
            #pragma unroll
            for (int m = 0; m < 3; ++m)
                if (live[m])
                    #pragma unroll
                    for (int i = 0; i < 4; ++i)
                        part[m][i] += fmaxf(acc[m][n][i] + b1v, 0.f) * w2v;
        }
        #pragma unroll
        for (int sh = 1; sh < 16; sh <<= 1)
            #pragma unroll
            for (int m = 0; m < 3; ++m)
                #pragma unroll
                for (int i = 0; i < 4; ++i)
                    part[m][i] += __shfl_xor(part[m][i], sh, 64);
        if (la == 0) {
            #pragma unroll
            for (int m = 0; m < 3; ++m)
                if (live[m])
                    #pragma unroll
                    for (int i = 0; i < 4; ++i) {
                        const int row = row0[m] + kg * 4 + i;
                        if (row < ne) logit_s[row] = part[m][i] + b2v;
                    }
        }
    }
    __syncthreads();

    // ---- block-local segment softmax: logit_s -> coef ----
    {
        const float p = powp[0];
        for (int s = s0 + wv; s < s1; s += 4) {
            const int a0 = starts[s] - e0;
            const int a1 = ((s + 1 < N) ? starts[s + 1] : E) - e0;
            if (a1 <= a0) continue;
            float mx = -3.4e38f;
            for (int idx = a0 + lane; idx < a1; idx += 64)
                mx = fmaxf(mx, logit_s[idx]);
            #pragma unroll
            for (int sh = 1; sh < 64; sh <<= 1)
                mx = fmaxf(mx, __shfl_xor(mx, sh, 64));
            float sum = 0.f;
            for (int idx = a0 + lane; idx < a1; idx += 64) {
                const float w = nodew[nbr_s[idx]];
                const float g = __expf(p * __logf(w) + (logit_s[idx] - mx));
                logit_s[idx] = g;   // same lane read->write: safe
                sum += g;
            }
            #pragma unroll
            for (int sh = 1; sh < 64; sh <<= 1)
                sum += __shfl_xor(sum, sh, 64);
            const float inv = 1.f / (sum + 1e-10f);
            for (int idx = a0 + lane; idx < a1; idx += 64)
                logit_s[idx] *= inv;
        }
    }
    __syncthreads();   // logit_s now holds coef for all rows

    // ---- GEMM1 msg: acc = msg @ mw1 ----
    #pragma unroll
    for (int m = 0; m < 3; ++m)
        #pragma unroll
        for (int n = 0; n < 8; ++n)
            acc[m][n] = f32x4{0.f, 0.f, 0.f, 0.f};
    #pragma unroll
    for (int kk = 0; kk < 4; ++kk) {
        const int kbase = kk * 32 + kg * 8;
        bf16x8 a[3];
        #pragma unroll
        for (int m = 0; m < 3; ++m)
            if (live[m]) a[m] = *reinterpret_cast<const bf16x8*>(&msg[row0[m] + la][kbase]);
        #pragma unroll
        for (int n = 0; n < 8; ++n) {
            bf16x8 bb = *reinterpret_cast<const bf16x8*>(mw1t + (size_t)(n * 16 + la) * HID + kbase);
            #pragma unroll
            for (int m = 0; m < 3; ++m)
                if (live[m]) acc[m][n] = __builtin_amdgcn_mfma_f32_16x16x32_bf16(a[m], bb, acc[m][n], 0, 0, 0);
        }
    }

    // ---- h = relu(acc + mb1) -> bf16, overwrite own rows in place ----
    #pragma unroll
    for (int n = 0; n < 8; ++n) {
        const float b1v = mb1[n * 16 + la];
        #pragma unroll
        for (int m = 0; m < 3; ++m)
            if (live[m])
                #pragma unroll
                for (int i = 0; i < 4; ++i)
                    msg[row0[m] + kg * 4 + i][n * 16 + la] =
                        (__bf16)fmaxf(acc[m][n][i] + b1v, 0.f);
    }
    asm volatile("" ::: "memory");

    // ---- GEMM2: x = h @ mw2 ----
    f32x4 c2[3][4] = {};
    #pragma unroll
    for (int kk = 0; kk < 4; ++kk) {
        const int kbase = kk * 32 + kg * 8;
        bf16x8 a[3];
        #pragma unroll
        for (int m = 0; m < 3; ++m)
            if (live[m]) a[m] = *reinterpret_cast<const bf16x8*>(&msg[row0[m] + la][kbase]);
        #pragma unroll
        for (int n = 0; n < 4; ++n) {
            bf16x8 bb = *reinterpret_cast<const bf16x8*>(mw2t + (size_t)(n * 16 + la) * HID + kbase);
            #pragma unroll
            for (int m = 0; m < 3; ++m)
                if (live[m]) c2[m][n] = __builtin_amdgcn_mfma_f32_16x16x32_bf16(a[m], bb, c2[m][n], 0, 0, 0);
        }
    }
    asm volatile("" ::: "memory");

    // ---- gated message -> f32 xb (aliases msg; own rows only) ----
    float (*xb)[68] = reinterpret_cast<float(*)[68]>(&msg[0][0]);
    #pragma unroll
    for (int m = 0; m < 3; ++m) {
        if (!live[m]) continue;
        float cf[4];
        #pragma unroll
        for (int i = 0; i < 4; ++i) {
            const int row = row0[m] + kg * 4 + i;
            cf[i] = (row < ne) ? logit_s[row] : 0.f;
        }
        #pragma unroll
        for (int n = 0; n < 4; ++n) {
            const float b2v = mb2[n * 16 + la];
            #pragma unroll
            for (int i = 0; i < 4; ++i)
                xb[row0[m] + kg * 4 + i][n * 16 + la] = cf[i] * (c2[m][n][i] + b2v);
        }
    }
    __syncthreads();

    // ---- per-segment column sum + non-atomic store ----
    for (int s = s0 + wv; s < s1; s += 4) {
        const int a0 = starts[s] - e0;
        const int a1 = ((s + 1 < N) ? starts[s + 1] : E) - e0;
        if (a1 <= a0) continue;
        float sum = 0.f;
        for (int r = a0; r < a1; ++r) sum += xb[r][lane];
        const size_t o = (size_t)s * D_FEAT + lane;
        out[o] = prev[o] + sum;
    }
}

extern "C" void kernel_launch(void* const* d_in, const int* in_sizes, int n_in,
                              void* d_out, int out_size, void* d_ws, size_t ws_size,
                              hipStream_t stream)
{
    const float* node_w = (const float*)d_in[0];
    const float* prev   = (const float*)d_in[1];
    const int*   selfi  = (const int*)d_in[2];
    const int*   nbri   = (const int*)d_in[3];
    const float* gw1 = (const float*)d_in[4];
    const float* gb1 = (const float*)d_in[5];
    const float* gw2 = (const float*)d_in[6];
    const float* gb2 = (const float*)d_in[7];
    const float* mw1 = (const float*)d_in[8];
    const float* mb1 = (const float*)d_in[9];
    const float* mw2 = (const float*)d_in[10];
    const float* mb2 = (const float*)d_in[11];
    const float* powp = (const float*)d_in[12];
    const int N = in_sizes[0];
    const int E = in_sizes[2];
    float* out = (float*)d_out;
    const int NB = (E + WIN - 1) / WIN;

    char* ws = (char*)d_ws;
    size_t off = 0;
    auto alloc = [&](size_t bytes) {
        void* p = ws + off;
        off = (off + bytes + 255) & ~(size_t)255;
        return p;
    };
    __bf16* featb  = (__bf16*)alloc((size_t)N * D_FEAT * 2);
    __bf16* gw1t   = (__bf16*)alloc(128 * 128 * 2);
    __bf16* mw1t   = (__bf16*)alloc(128 * 128 * 2);
    __bf16* mw2t   = (__bf16*)alloc(64 * 128 * 2);
    int* self_p    = (int*)alloc((size_t)E * 4);
    int* nbr_p     = (int*)alloc((size_t)E * 4);
    int* hist      = (int*)alloc((size_t)N * 4);
    int* cursor    = (int*)alloc((size_t)N * 4);
    int* starts    = (int*)alloc((size_t)N * 4);
    int* incl      = (int*)alloc((size_t)N * 4);
    int* s_lo      = (int*)alloc((size_t)NB * 4);
    int* s_hi      = (int*)alloc((size_t)NB * 4);
    const int nb = (N + SCAN_BLK - 1) / SCAN_BLK;
    int* bsum      = (int*)alloc((size_t)nb * 4);
    int* boff      = (int*)alloc((size_t)nb * 4);

    const int totalF = N * D_FEAT;
    k_init<<<(totalF + 255) / 256, 256, 0, stream>>>(prev, out, featb, hist, s_lo, s_hi, totalF, N, NB);
    k_wconv<<<(40960 + 255) / 256, 256, 0, stream>>>(gw1, mw1, mw2, gw1t, mw1t, mw2t);
    k_hist<<<(E + 255) / 256, 256, 0, stream>>>(selfi, hist, E);
    k_scan1<<<nb, SCAN_BLK, 0, stream>>>(hist, incl, bsum, N);
    k_scan2<<<1, 64, 0, stream>>>(bsum, boff, nb);
    k_scan3<<<nb, SCAN_BLK, 0, stream>>>(incl, hist, boff, cursor, starts, N);
    k_scatter<<<(E + 255) / 256, 256, 0, stream>>>(selfi, nbri, cursor, self_p, nbr_p, E);
    k_blockmeta<<<(N + 255) / 256, 256, 0, stream>>>(starts, s_lo, s_hi, N, E);
    k_fused<<<NB, 256, 0, stream>>>(featb, self_p, nbr_p, starts, s_lo, s_hi,
                                    node_w, powp, gw1t, gb1, gw2, gb2,
                                    mw1t, mb1, mw2t, mb2, prev, out, N, E);
}

// Round 4
// 679.657 us; speedup vs baseline: 1.3091x; 1.2529x over previous
//
#include <hip/hip_runtime.h>
#include <hip/hip_bf16.h>

typedef __bf16 bf16x8 __attribute__((ext_vector_type(8)));
typedef __bf16 bf16x4 __attribute__((ext_vector_type(4)));
typedef float f32x4 __attribute__((ext_vector_type(4)));

#define WIN 64           // edge window per block (segment starts)
#define TILE 112         // WIN-1 + max_degree(<=49)
#define LSTR 136         // bf16 row stride (272B): 16B aligned, 2-way bank alias (free)
#define TROW 512         // T row: [Pg(128)|Qg(128)|Pm(128)|Qm(128)]
#define SCAN_BLK 1024

__global__ void k_init0(int* __restrict__ hist, int* __restrict__ s_lo,
                        int* __restrict__ s_hi, int N, int NB)
{
    int i = blockIdx.x * 256 + threadIdx.x;
    if (i < N) hist[i] = 0;
    if (i < NB) { s_lo[i] = 0x7fffffff; s_hi[i] = 0; }
}

// Bt[c][k] (512x64 bf16): c<128 gw1_top, <256 gw1_bot, <384 mw1_top, else mw1_bot.
// mw2t[c][k] (64x128 bf16) for GEMM2.
__global__ void k_wconv(const float* __restrict__ gw1, const float* __restrict__ mw1,
                        const float* __restrict__ mw2,
                        __bf16* __restrict__ Bt, __bf16* __restrict__ mw2t)
{
    int i = blockIdx.x * 256 + threadIdx.x;
    if (i < 32768) {
        int c = i >> 6, k = i & 63;
        float v;
        if (c < 128)      v = gw1[k * 128 + c];
        else if (c < 256) v = gw1[(64 + k) * 128 + (c - 128)];
        else if (c < 384) v = mw1[k * 128 + (c - 256)];
        else              v = mw1[(64 + k) * 128 + (c - 384)];
        Bt[i] = (__bf16)v;
    } else if (i < 40960) {
        int j = i - 32768;
        int c = j >> 7, k = j & 127;
        mw2t[j] = (__bf16)mw2[k * 64 + c];
    }
}

// T = feat @ [gw1_top|gw1_bot|mw1_top|mw1_bot] (+biases folded into P halves)
__global__ void __launch_bounds__(256, 4)
k_tab(const float* __restrict__ feat, const __bf16* __restrict__ Bt,
      const float* __restrict__ gb1, const float* __restrict__ mb1,
      __bf16* __restrict__ T, int N)
{
    const int tid = threadIdx.x;
    const int lane = tid & 63, wv = tid >> 6;
    const int la = lane & 15, kg = lane >> 4;
    const int r0 = blockIdx.x * 16;

    bf16x8 a[2];
    #pragma unroll
    for (int kk = 0; kk < 2; ++kk) {
        const float* src = feat + (size_t)(r0 + la) * 64 + kk * 32 + kg * 8;
        f32x4 f0 = *reinterpret_cast<const f32x4*>(src);
        f32x4 f1 = *reinterpret_cast<const f32x4*>(src + 4);
        #pragma unroll
        for (int j = 0; j < 4; ++j) { a[kk][j] = (__bf16)f0[j]; a[kk][4 + j] = (__bf16)f1[j]; }
    }
    #pragma unroll
    for (int j = 0; j < 8; ++j) {
        const int c = wv * 128 + j * 16 + la;
        float bias = 0.f;
        if (c < 128) bias = gb1[c];
        else if (c >= 256 && c < 384) bias = mb1[c - 256];
        f32x4 acc = {bias, bias, bias, bias};
        #pragma unroll
        for (int kk = 0; kk < 2; ++kk) {
            bf16x8 bb = *reinterpret_cast<const bf16x8*>(Bt + (size_t)c * 64 + kk * 32 + kg * 8);
            acc = __builtin_amdgcn_mfma_f32_16x16x32_bf16(a[kk], bb, acc, 0, 0, 0);
        }
        #pragma unroll
        for (int i = 0; i < 4; ++i)
            T[(size_t)(r0 + kg * 4 + i) * TROW + c] = (__bf16)acc[i];
    }
}

// ---- counting sort by self_idx ----
__global__ void k_hist(const int* __restrict__ selfi, int* __restrict__ hist, int E)
{
    int e = blockIdx.x * 256 + threadIdx.x;
    if (e < E) atomicAdd(&hist[selfi[e]], 1);
}

__global__ void k_scan1(const int* __restrict__ hist, int* __restrict__ incl,
                        int* __restrict__ bsum, int N)
{
    __shared__ int sd[SCAN_BLK];
    int i = blockIdx.x * SCAN_BLK + threadIdx.x;
    int v = (i < N) ? hist[i] : 0;
    sd[threadIdx.x] = v;
    __syncthreads();
    #pragma unroll
    for (int off = 1; off < SCAN_BLK; off <<= 1) {
        int t = (threadIdx.x >= off) ? sd[threadIdx.x - off] : 0;
        __syncthreads();
        sd[threadIdx.x] += t;
        __syncthreads();
    }
    if (i < N) incl[i] = sd[threadIdx.x];
    if (threadIdx.x == SCAN_BLK - 1) bsum[blockIdx.x] = sd[SCAN_BLK - 1];
}

__global__ void k_scan2(int* __restrict__ bsum, int* __restrict__ boff, int nb)
{
    if (threadIdx.x == 0 && blockIdx.x == 0) {
        int run = 0;
        for (int j = 0; j < nb; ++j) { boff[j] = run; run += bsum[j]; }
    }
}

__global__ void k_scan3(const int* __restrict__ incl, const int* __restrict__ hist,
                        const int* __restrict__ boff, int* __restrict__ cursor,
                        int* __restrict__ starts, int N)
{
    int i = blockIdx.x * SCAN_BLK + threadIdx.x;
    if (i < N) {
        int v = incl[i] - hist[i] + boff[blockIdx.x];
        cursor[i] = v;
        starts[i] = v;
    }
}

__global__ void k_scatter(const int* __restrict__ selfi, const int* __restrict__ nbri,
                          int* __restrict__ cursor, int* __restrict__ self_p,
                          int* __restrict__ nbr_p, int E)
{
    int e = blockIdx.x * 256 + threadIdx.x;
    if (e >= E) return;
    int s = selfi[e];
    int pos = atomicAdd(&cursor[s], 1);
    self_p[pos] = s;
    nbr_p[pos] = nbri[e];
}

__global__ void k_blockmeta(const int* __restrict__ starts, int* __restrict__ s_lo,
                            int* __restrict__ s_hi, int N, int E)
{
    int s = blockIdx.x * 256 + threadIdx.x;
    if (s >= N) return;
    int st = starts[s];
    int en = (s + 1 < N) ? starts[s + 1] : E;
    if (en <= st) return;
    int b = st / WIN;
    atomicMin(&s_lo[b], s);
    atomicMax(&s_hi[b], s + 1);
}

// zero-degree nodes: out = prev
__global__ void k_tail(const int* __restrict__ hist, const float* __restrict__ prev,
                       float* __restrict__ out, int total)
{
    int i = blockIdx.x * 256 + threadIdx.x;
    if (i < total && hist[i >> 6] == 0) out[i] = prev[i];
}

// ---- fused edge kernel: gather T -> logits + h -> block-local softmax
//      -> GEMM2 -> gated segment sum -> non-atomic store ----
__global__ void __launch_bounds__(256, 5)
k_fused(const __bf16* __restrict__ T,
        const int* __restrict__ self_p, const int* __restrict__ nbr_p,
        const int* __restrict__ starts,
        const int* __restrict__ s_lo, const int* __restrict__ s_hi,
        const float* __restrict__ nodew, const float* __restrict__ powp,
        const float* __restrict__ gw2, const float* __restrict__ gb2,
        const __bf16* __restrict__ mw2t, const float* __restrict__ mb2,
        const float* __restrict__ prev, float* __restrict__ out,
        int N, int E)
{
    __shared__ __align__(16) __bf16 hlds[TILE][LSTR];  // h (bf16), later xb f32 [TILE][68]
    __shared__ float logit_s[TILE];                    // logit -> coef
    __shared__ int nbr_s[TILE];

    const int b = blockIdx.x;
    const int s0 = s_lo[b];
    if (s0 == 0x7fffffff) return;
    const int s1 = s_hi[b];
    const int e0 = starts[s0];
    const int e1 = (s1 < N) ? starts[s1] : E;
    int ne = e1 - e0;
    if (ne > TILE) ne = TILE;   // astronomically unlikely safety clamp

    const int tid = threadIdx.x;
    const int lane = tid & 63, wv = tid >> 6;
    const int hw = lane >> 5, il = lane & 31;
    const int c4 = il * 4;

    // ---- phase 1: per-edge hidden (h -> LDS) + gate logit (half-wave per row) ----
    {
        const f32x4 w2v = *reinterpret_cast<const f32x4*>(gw2 + c4);
        const float b2v = gb2[0];
        for (int r = wv * 2 + hw; r < ne; r += 8) {
            const int ge = e0 + r;
            const int sn = self_p[ge];
            const int nb = nbr_p[ge];
            const __bf16* Ts = T + (size_t)sn * TROW;
            const __bf16* Tn = T + (size_t)nb * TROW;
            bf16x4 pg = *reinterpret_cast<const bf16x4*>(Ts + c4);
            bf16x4 qg = *reinterpret_cast<const bf16x4*>(Tn + 128 + c4);
            bf16x4 pm = *reinterpret_cast<const bf16x4*>(Ts + 256 + c4);
            bf16x4 qm = *reinterpret_cast<const bf16x4*>(Tn + 384 + c4);
            float lg = 0.f;
            bf16x4 hv;
            #pragma unroll
            for (int j = 0; j < 4; ++j) {
                const float hg = fmaxf((float)pg[j] + (float)qg[j], 0.f);
                lg = fmaf(hg, w2v[j], lg);
                const float hm = fmaxf((float)pm[j] + (float)qm[j], 0.f);
                hv[j] = (__bf16)hm;
            }
            *reinterpret_cast<bf16x4*>(&hlds[r][c4]) = hv;
            #pragma unroll
            for (int sh = 1; sh < 32; sh <<= 1)
                lg += __shfl_xor(lg, sh, 64);
            if (il == 0) {
                logit_s[r] = lg + b2v;
                nbr_s[r] = nb;
            }
        }
    }
    __syncthreads();

    // ---- phase 2: block-local segment softmax ----
    {
        const float p = powp[0];
        for (int s = s0 + wv; s < s1; s += 4) {
            int a0 = starts[s] - e0;
            int a1 = ((s + 1 < N) ? starts[s + 1] : E) - e0;
            if (a1 > ne) a1 = ne;
            if (a1 <= a0) continue;
            float mx = -3.4e38f;
            for (int idx = a0 + lane; idx < a1; idx += 64)
                mx = fmaxf(mx, logit_s[idx]);
            #pragma unroll
            for (int sh = 1; sh < 64; sh <<= 1)
                mx = fmaxf(mx, __shfl_xor(mx, sh, 64));
            float sum = 0.f;
            for (int idx = a0 + lane; idx < a1; idx += 64) {
                const float w = nodew[nbr_s[idx]];
                const float g = __expf(p * __logf(w) + (logit_s[idx] - mx));
                logit_s[idx] = g;
                sum += g;
            }
            #pragma unroll
            for (int sh = 1; sh < 64; sh <<= 1)
                sum += __shfl_xor(sum, sh, 64);
            const float inv = 1.f / (sum + 1e-10f);
            for (int idx = a0 + lane; idx < a1; idx += 64)
                logit_s[idx] *= inv;
        }
    }
    __syncthreads();   // logit_s = coef; hlds = h (cross-wave visible)

    // ---- phase 3: GEMM2 x = h @ mw2 (7 m-tiles over 4 waves) ----
    const int la = lane & 15, kg = lane >> 4;
    const int row0[2] = {wv * 16, 64 + wv * 16};
    const bool lv[2] = {row0[0] < ne, (wv < 3) && (row0[1] < ne)};

    f32x4 c2[2][4] = {};
    #pragma unroll
    for (int kk = 0; kk < 4; ++kk) {
        const int kbase = kk * 32 + kg * 8;
        bf16x8 a[2];
        #pragma unroll
        for (int m = 0; m < 2; ++m)
            if (lv[m]) a[m] = *reinterpret_cast<const bf16x8*>(&hlds[row0[m] + la][kbase]);
        #pragma unroll
        for (int n = 0; n < 4; ++n) {
            bf16x8 bb = *reinterpret_cast<const bf16x8*>(mw2t + (size_t)(n * 16 + la) * 128 + kbase);
            #pragma unroll
            for (int m = 0; m < 2; ++m)
                if (lv[m]) c2[m][n] = __builtin_amdgcn_mfma_f32_16x16x32_bf16(a[m], bb, c2[m][n], 0, 0, 0);
        }
    }
    asm volatile("" ::: "memory");

    // gated message -> f32 xb (aliases hlds; wave-local rows)
    float (*xb)[68] = reinterpret_cast<float(*)[68]>(&hlds[0][0]);
    #pragma unroll
    for (int m = 0; m < 2; ++m) {
        if (!lv[m]) continue;
        float cf[4];
        #pragma unroll
        for (int i = 0; i < 4; ++i) {
            const int row = row0[m] + kg * 4 + i;
            cf[i] = (row < ne) ? logit_s[row] : 0.f;
        }
        #pragma unroll
        for (int n = 0; n < 4; ++n) {
            const float b2v = mb2[n * 16 + la];
            #pragma unroll
            for (int i = 0; i < 4; ++i)
                xb[row0[m] + kg * 4 + i][n * 16 + la] = cf[i] * (c2[m][n][i] + b2v);
        }
    }
    __syncthreads();

    // ---- per-segment column sum + non-atomic store ----
    for (int s = s0 + wv; s < s1; s += 4) {
        int a0 = starts[s] - e0;
        int a1 = ((s + 1 < N) ? starts[s + 1] : E) - e0;
        if (a1 > ne) a1 = ne;
        if (a1 <= a0) continue;
        float sum = 0.f;
        for (int r = a0; r < a1; ++r) sum += xb[r][lane];
        const size_t o = (size_t)s * 64 + lane;
        out[o] = prev[o] + sum;
    }
}

extern "C" void kernel_launch(void* const* d_in, const int* in_sizes, int n_in,
                              void* d_out, int out_size, void* d_ws, size_t ws_size,
                              hipStream_t stream)
{
    const float* node_w = (const float*)d_in[0];
    const float* prev   = (const float*)d_in[1];
    const int*   selfi  = (const int*)d_in[2];
    const int*   nbri   = (const int*)d_in[3];
    const float* gw1 = (const float*)d_in[4];
    const float* gb1 = (const float*)d_in[5];
    const float* gw2 = (const float*)d_in[6];
    const float* gb2 = (const float*)d_in[7];
    const float* mw1 = (const float*)d_in[8];
    const float* mb1 = (const float*)d_in[9];
    const float* mw2 = (const float*)d_in[10];
    const float* mb2 = (const float*)d_in[11];
    const float* powp = (const float*)d_in[12];
    const int N = in_sizes[0];
    const int E = in_sizes[2];
    float* out = (float*)d_out;
    const int NB = (E + WIN - 1) / WIN;

    char* ws = (char*)d_ws;
    size_t off = 0;
    auto alloc = [&](size_t bytes) {
        void* p = ws + off;
        off = (off + bytes + 255) & ~(size_t)255;
        return p;
    };
    __bf16* T      = (__bf16*)alloc((size_t)N * TROW * 2);   // 102.4 MB
    __bf16* Bt     = (__bf16*)alloc(512 * 64 * 2);
    __bf16* mw2t   = (__bf16*)alloc(64 * 128 * 2);
    int* self_p    = (int*)alloc((size_t)E * 4);
    int* nbr_p     = (int*)alloc((size_t)E * 4);
    int* hist      = (int*)alloc((size_t)N * 4);
    int* cursor    = (int*)alloc((size_t)N * 4);
    int* starts    = (int*)alloc((size_t)N * 4);
    int* incl      = (int*)alloc((size_t)N * 4);
    int* s_lo      = (int*)alloc((size_t)NB * 4);
    int* s_hi      = (int*)alloc((size_t)NB * 4);
    const int nb = (N + SCAN_BLK - 1) / SCAN_BLK;
    int* bsum      = (int*)alloc((size_t)nb * 4);
    int* boff      = (int*)alloc((size_t)nb * 4);

    const int totalF = N * 64;
    k_init0<<<(N + 255) / 256, 256, 0, stream>>>(hist, s_lo, s_hi, N, NB);
    k_wconv<<<160, 256, 0, stream>>>(gw1, mw1, mw2, Bt, mw2t);
    k_tab<<<N / 16, 256, 0, stream>>>(prev, Bt, gb1, mb1, T, N);
    k_hist<<<(E + 255) / 256, 256, 0, stream>>>(selfi, hist, E);
    k_scan1<<<nb, SCAN_BLK, 0, stream>>>(hist, incl, bsum, N);
    k_scan2<<<1, 64, 0, stream>>>(bsum, boff, nb);
    k_scan3<<<nb, SCAN_BLK, 0, stream>>>(incl, hist, boff, cursor, starts, N);
    k_scatter<<<(E + 255) / 256, 256, 0, stream>>>(selfi, nbri, cursor, self_p, nbr_p, E);
    k_blockmeta<<<(N + 255) / 256, 256, 0, stream>>>(starts, s_lo, s_hi, N, E);
    k_tail<<<(totalF + 255) / 256, 256, 0, stream>>>(hist, prev, out, totalF);
    k_fused<<<NB, 256, 0, stream>>>(T, self_p, nbr_p, starts, s_lo, s_hi,
                                    node_w, powp, gw2, gb2, mw2t, mb2, prev, out, N, E);
}

// Round 5
// 625.772 us; speedup vs baseline: 1.4219x; 1.0861x over previous
//
#include <hip/hip_runtime.h>
#include <hip/hip_bf16.h>

typedef __bf16 bf16x8 __attribute__((ext_vector_type(8)));
typedef __bf16 bf16x4 __attribute__((ext_vector_type(4)));
typedef float f32x4 __attribute__((ext_vector_type(4)));

#define WIN 64           // edge window per block (segment starts)
#define TILE 112         // WIN-1 + max_degree(<=49)
#define LSTR 136         // bf16 row stride (272B): 16B aligned
#define SCAN_BLK 1024
#define SENT 0x7f7f7f7f

// Bt[c][k] (512x64 bf16): c<128 gw1_top, <256 gw1_bot, <384 mw1_top, else mw1_bot.
// mw2t[c][k] (64x128 bf16) for GEMM2.
__global__ void k_wconv(const float* __restrict__ gw1, const float* __restrict__ mw1,
                        const float* __restrict__ mw2,
                        __bf16* __restrict__ Bt, __bf16* __restrict__ mw2t)
{
    int i = blockIdx.x * 256 + threadIdx.x;
    if (i < 32768) {
        int c = i >> 6, k = i & 63;
        float v;
        if (c < 128)      v = gw1[k * 128 + c];
        else if (c < 256) v = gw1[(64 + k) * 128 + (c - 128)];
        else if (c < 384) v = mw1[k * 128 + (c - 256)];
        else              v = mw1[(64 + k) * 128 + (c - 384)];
        Bt[i] = (__bf16)v;
    } else if (i < 40960) {
        int j = i - 32768;
        int c = j >> 7, k = j & 127;
        mw2t[j] = (__bf16)mw2[k * 64 + c];
    }
}

// Split tables: Tp[n][256] = [Pg|Pm] (self part, biases folded),
//               Tq[n][256] = [Qg|Qm] (neighbor part).
// Also fused: edge histogram (grid-stride).
__global__ void __launch_bounds__(256, 4)
k_tab(const float* __restrict__ feat, const __bf16* __restrict__ Bt,
      const float* __restrict__ gb1, const float* __restrict__ mb1,
      const int* __restrict__ selfi, int* __restrict__ hist,
      __bf16* __restrict__ Tp, __bf16* __restrict__ Tq, int N, int E)
{
    for (int e = blockIdx.x * 256 + threadIdx.x; e < E; e += gridDim.x * 256)
        atomicAdd(&hist[selfi[e]], 1);

    const int tid = threadIdx.x;
    const int lane = tid & 63, wv = tid >> 6;
    const int la = lane & 15, kg = lane >> 4;
    const int r0 = blockIdx.x * 16;
    if (r0 >= N) return;

    bf16x8 a[2];
    #pragma unroll
    for (int kk = 0; kk < 2; ++kk) {
        const int rr = min(r0 + la, N - 1);
        const float* src = feat + (size_t)rr * 64 + kk * 32 + kg * 8;
        f32x4 f0 = *reinterpret_cast<const f32x4*>(src);
        f32x4 f1 = *reinterpret_cast<const f32x4*>(src + 4);
        #pragma unroll
        for (int j = 0; j < 4; ++j) { a[kk][j] = (__bf16)f0[j]; a[kk][4 + j] = (__bf16)f1[j]; }
    }
    #pragma unroll
    for (int j = 0; j < 8; ++j) {
        const int c = wv * 128 + j * 16 + la;
        float bias = 0.f;
        if (c < 128) bias = gb1[c];
        else if (c >= 256 && c < 384) bias = mb1[c - 256];
        f32x4 acc = {bias, bias, bias, bias};
        #pragma unroll
        for (int kk = 0; kk < 2; ++kk) {
            bf16x8 bb = *reinterpret_cast<const bf16x8*>(Bt + (size_t)c * 64 + kk * 32 + kg * 8);
            acc = __builtin_amdgcn_mfma_f32_16x16x32_bf16(a[kk], bb, acc, 0, 0, 0);
        }
        #pragma unroll
        for (int i = 0; i < 4; ++i) {
            const int row = r0 + kg * 4 + i;
            if (row < N) {
                const __bf16 v = (__bf16)acc[i];
                if (c < 128)      Tp[(size_t)row * 256 + c] = v;
                else if (c < 256) Tq[(size_t)row * 256 + (c - 128)] = v;
                else if (c < 384) Tp[(size_t)row * 256 + 128 + (c - 256)] = v;
                else              Tq[(size_t)row * 256 + 128 + (c - 384)] = v;
            }
        }
    }
}

__global__ void k_scan1(const int* __restrict__ hist, int* __restrict__ incl,
                        int* __restrict__ bsum, int N)
{
    __shared__ int sd[SCAN_BLK];
    int i = blockIdx.x * SCAN_BLK + threadIdx.x;
    int v = (i < N) ? hist[i] : 0;
    sd[threadIdx.x] = v;
    __syncthreads();
    for (int off = 1; off < SCAN_BLK; off <<= 1) {
        int t = (threadIdx.x >= off) ? sd[threadIdx.x - off] : 0;
        __syncthreads();
        sd[threadIdx.x] += t;
        __syncthreads();
    }
    if (i < N) incl[i] = sd[threadIdx.x];
    if (threadIdx.x == SCAN_BLK - 1) bsum[blockIdx.x] = sd[SCAN_BLK - 1];
}

// merged: scan finalize + block meta + wp precompute + zero-degree out copy
__global__ void k_scan23(const int* __restrict__ incl, const int* __restrict__ hist,
                         const int* __restrict__ bsum,
                         int* __restrict__ cursor, int* __restrict__ starts,
                         int* __restrict__ s_lo, int* __restrict__ s_hi,
                         float* __restrict__ wp, const float* __restrict__ nodew,
                         const float* __restrict__ powp,
                         const float* __restrict__ prev, float* __restrict__ out,
                         int N, int E)
{
    __shared__ int boff_s;
    if (threadIdx.x == 0) {
        int run = 0;
        for (int j = 0; j < (int)blockIdx.x; ++j) run += bsum[j];
        boff_s = run;
    }
    __syncthreads();
    int i = blockIdx.x * SCAN_BLK + threadIdx.x;
    if (i >= N) return;
    const int h = hist[i];
    const int v = incl[i] - h + boff_s;
    cursor[i] = v;
    starts[i] = v;
    wp[i] = __powf(nodew[i], powp[0]);
    if (h > 0) {
        const int b = v / WIN;
        atomicMin(&s_lo[b], i);
        atomicMax(&s_hi[b], i + 1);
    } else {
        // zero-degree node (astronomically rare): out = prev
        const float* ps = prev + (size_t)i * 64;
        float* po = out + (size_t)i * 64;
        for (int k = 0; k < 64; ++k) po[k] = ps[k];
    }
}

__global__ void k_scatter(const int* __restrict__ selfi, const int* __restrict__ nbri,
                          int* __restrict__ cursor, int2* __restrict__ edge_p, int E)
{
    int e = blockIdx.x * 256 + threadIdx.x;
    if (e >= E) return;
    int s = selfi[e];
    int pos = atomicAdd(&cursor[s], 1);
    edge_p[pos] = make_int2(s, nbri[e]);
}

// ---- fused edge kernel ----
__global__ void __launch_bounds__(256, 5)
k_fused(const __bf16* __restrict__ Tp, const __bf16* __restrict__ Tq,
        const int2* __restrict__ edge_p, const int* __restrict__ starts,
        const int* __restrict__ s_lo, const int* __restrict__ s_hi,
        const float* __restrict__ wp,
        const float* __restrict__ gw2, const float* __restrict__ gb2,
        const __bf16* __restrict__ mw2t, const float* __restrict__ mb2,
        const float* __restrict__ prev, float* __restrict__ out,
        int N, int E)
{
    __shared__ __align__(16) __bf16 hlds[TILE][LSTR];  // h (bf16), later xb f32 [TILE][68]
    __shared__ int2 edge_s[TILE];
    __shared__ float logit_s[TILE];                    // logit -> coef
    __shared__ float nbrw_s[TILE];                     // w^p per edge

    const int b = blockIdx.x;
    const int s0 = s_lo[b];
    if (s0 == SENT) return;
    const int s1 = s_hi[b];
    const int e0 = starts[s0];
    const int e1 = (s1 < N) ? starts[s1] : E;
    int ne = e1 - e0;
    if (ne > TILE) ne = TILE;   // safety clamp

    const int tid = threadIdx.x;
    for (int i = tid; i < ne; i += 256) edge_s[i] = edge_p[e0 + i];
    __syncthreads();

    const int lane = tid & 63, wv = tid >> 6;
    const int hw8 = tid >> 5, il = tid & 31;
    const int c4 = il * 4;

    // ---- phase 1: contiguous chunk per half-wave; self regs cached across edges;
    //      q-gathers software-pipelined ----
    {
        const f32x4 w2v = *reinterpret_cast<const f32x4*>(gw2 + c4);
        const float b2v = gb2[0];
        const int ck = (ne + 7) >> 3;
        int r = hw8 * ck;
        const int re = min(r + ck, ne);
        int prev_sn = -1;
        int2 eg = make_int2(0, 0);
        bf16x4 pg = {}, pm = {}, qg = {}, qm = {};
        if (r < re) {
            eg = edge_s[r];
            const __bf16* tq = Tq + (size_t)eg.y * 256 + c4;
            qg = *reinterpret_cast<const bf16x4*>(tq);
            qm = *reinterpret_cast<const bf16x4*>(tq + 128);
        }
        while (r < re) {
            const int rn = r + 1;
            int2 egn = make_int2(0, 0);
            bf16x4 qgn = {}, qmn = {};
            if (rn < re) {
                egn = edge_s[rn];
                const __bf16* tq = Tq + (size_t)egn.y * 256 + c4;
                qgn = *reinterpret_cast<const bf16x4*>(tq);
                qmn = *reinterpret_cast<const bf16x4*>(tq + 128);
            }
            const float wpv = wp[eg.y];
            if (eg.x != prev_sn) {
                const __bf16* tp = Tp + (size_t)eg.x * 256 + c4;
                pg = *reinterpret_cast<const bf16x4*>(tp);
                pm = *reinterpret_cast<const bf16x4*>(tp + 128);
                prev_sn = eg.x;
            }
            float lg = 0.f;
            bf16x4 hv;
            #pragma unroll
            for (int j = 0; j < 4; ++j) {
                lg = fmaf(fmaxf((float)pg[j] + (float)qg[j], 0.f), w2v[j], lg);
                hv[j] = (__bf16)fmaxf((float)pm[j] + (float)qm[j], 0.f);
            }
            *reinterpret_cast<bf16x4*>(&hlds[r][c4]) = hv;
            #pragma unroll
            for (int sh = 1; sh < 32; sh <<= 1)
                lg += __shfl_xor(lg, sh, 64);
            if (il == 0) { logit_s[r] = lg + b2v; nbrw_s[r] = wpv; }
            eg = egn; qg = qgn; qm = qmn; r = rn;
        }
    }
    __syncthreads();

    // ---- phase 2: block-local segment softmax (pure LDS) ----
    {
        for (int s = s0 + wv; s < s1; s += 4) {
            int a0 = starts[s] - e0;
            int a1 = ((s + 1 < N) ? starts[s + 1] : E) - e0;
            if (a1 > ne) a1 = ne;
            if (a1 <= a0) continue;
            float mx = -3.4e38f;
            for (int idx = a0 + lane; idx < a1; idx += 64)
                mx = fmaxf(mx, logit_s[idx]);
            #pragma unroll
            for (int sh = 1; sh < 64; sh <<= 1)
                mx = fmaxf(mx, __shfl_xor(mx, sh, 64));
            float sum = 0.f;
            for (int idx = a0 + lane; idx < a1; idx += 64) {
                const float g = nbrw_s[idx] * __expf(logit_s[idx] - mx);
                logit_s[idx] = g;
                sum += g;
            }
            #pragma unroll
            for (int sh = 1; sh < 64; sh <<= 1)
                sum += __shfl_xor(sum, sh, 64);
            const float inv = 1.f / (sum + 1e-10f);
            for (int idx = a0 + lane; idx < a1; idx += 64)
                logit_s[idx] *= inv;
        }
    }
    __syncthreads();   // logit_s = coef; hlds = h

    // ---- phase 3: GEMM2 x = h @ mw2 (7 m-tiles over 4 waves) ----
    const int la = lane & 15, kg = lane >> 4;
    const int row0[2] = {wv * 16, 64 + wv * 16};
    const bool lv[2] = {row0[0] < ne, (wv < 3) && (row0[1] < ne)};

    f32x4 c2[2][4] = {};
    #pragma unroll
    for (int kk = 0; kk < 4; ++kk) {
        const int kbase = kk * 32 + kg * 8;
        bf16x8 a[2];
        #pragma unroll
        for (int m = 0; m < 2; ++m)
            if (lv[m]) a[m] = *reinterpret_cast<const bf16x8*>(&hlds[row0[m] + la][kbase]);
        #pragma unroll
        for (int n = 0; n < 4; ++n) {
            bf16x8 bb = *reinterpret_cast<const bf16x8*>(mw2t + (size_t)(n * 16 + la) * 128 + kbase);
            #pragma unroll
            for (int m = 0; m < 2; ++m)
                if (lv[m]) c2[m][n] = __builtin_amdgcn_mfma_f32_16x16x32_bf16(a[m], bb, c2[m][n], 0, 0, 0);
        }
    }
    asm volatile("" ::: "memory");

    float (*xb)[68] = reinterpret_cast<float(*)[68]>(&hlds[0][0]);
    #pragma unroll
    for (int m = 0; m < 2; ++m) {
        if (!lv[m]) continue;
        float cf[4];
        #pragma unroll
        for (int i = 0; i < 4; ++i) {
            const int row = row0[m] + kg * 4 + i;
            cf[i] = (row < ne) ? logit_s[row] : 0.f;
        }
        #pragma unroll
        for (int n = 0; n < 4; ++n) {
            const float b2v = mb2[n * 16 + la];
            #pragma unroll
            for (int i = 0; i < 4; ++i)
                xb[row0[m] + kg * 4 + i][n * 16 + la] = cf[i] * (c2[m][n][i] + b2v);
        }
    }
    __syncthreads();

    // ---- per-segment column sum + non-atomic store ----
    for (int s = s0 + wv; s < s1; s += 4) {
        int a0 = starts[s] - e0;
        int a1 = ((s + 1 < N) ? starts[s + 1] : E) - e0;
        if (a1 > ne) a1 = ne;
        if (a1 <= a0) continue;
        float sum = 0.f;
        for (int r = a0; r < a1; ++r) sum += xb[r][lane];
        const size_t o = (size_t)s * 64 + lane;
        out[o] = prev[o] + sum;
    }
}

extern "C" void kernel_launch(void* const* d_in, const int* in_sizes, int n_in,
                              void* d_out, int out_size, void* d_ws, size_t ws_size,
                              hipStream_t stream)
{
    const float* node_w = (const float*)d_in[0];
    const float* prev   = (const float*)d_in[1];
    const int*   selfi  = (const int*)d_in[2];
    const int*   nbri   = (const int*)d_in[3];
    const float* gw1 = (const float*)d_in[4];
    const float* gb1 = (const float*)d_in[5];
    const float* gw2 = (const float*)d_in[6];
    const float* gb2 = (const float*)d_in[7];
    const float* mw1 = (const float*)d_in[8];
    const float* mb1 = (const float*)d_in[9];
    const float* mw2 = (const float*)d_in[10];
    const float* mb2 = (const float*)d_in[11];
    const float* powp = (const float*)d_in[12];
    const int N = in_sizes[0];
    const int E = in_sizes[2];
    float* out = (float*)d_out;
    const int NB = (E + WIN - 1) / WIN;

    char* ws = (char*)d_ws;
    size_t off = 0;
    auto alloc = [&](size_t bytes) {
        void* p = ws + off;
        off = (off + bytes + 255) & ~(size_t)255;
        return p;
    };
    __bf16* Tp     = (__bf16*)alloc((size_t)N * 256 * 2);   // 51.2 MB
    __bf16* Tq     = (__bf16*)alloc((size_t)N * 256 * 2);   // 51.2 MB
    __bf16* Bt     = (__bf16*)alloc(512 * 64 * 2);
    __bf16* mw2t   = (__bf16*)alloc(64 * 128 * 2);
    int2* edge_p   = (int2*)alloc((size_t)E * 8);
    int* hist      = (int*)alloc((size_t)N * 4);
    int* cursor    = (int*)alloc((size_t)N * 4);
    int* starts    = (int*)alloc((size_t)N * 4);
    int* incl      = (int*)alloc((size_t)N * 4);
    float* wp      = (float*)alloc((size_t)N * 4);
    int* s_lo      = (int*)alloc((size_t)NB * 4);
    int* s_hi      = (int*)alloc((size_t)NB * 4);
    const int nb = (N + SCAN_BLK - 1) / SCAN_BLK;
    int* bsum      = (int*)alloc((size_t)nb * 4);

    hipMemsetAsync(hist, 0, (size_t)N * 4, stream);
    hipMemsetAsync(s_lo, 0x7f, (size_t)NB * 4, stream);
    hipMemsetAsync(s_hi, 0, (size_t)NB * 4, stream);

    k_wconv<<<160, 256, 0, stream>>>(gw1, mw1, mw2, Bt, mw2t);
    k_tab<<<(N + 15) / 16, 256, 0, stream>>>(prev, Bt, gb1, mb1, selfi, hist, Tp, Tq, N, E);
    k_scan1<<<nb, SCAN_BLK, 0, stream>>>(hist, incl, bsum, N);
    k_scan23<<<nb, SCAN_BLK, 0, stream>>>(incl, hist, bsum, cursor, starts, s_lo, s_hi,
                                          wp, node_w, powp, prev, out, N, E);
    k_scatter<<<(E + 255) / 256, 256, 0, stream>>>(selfi, nbri, cursor, edge_p, E);
    k_fused<<<NB, 256, 0, stream>>>(Tp, Tq, edge_p, starts, s_lo, s_hi, wp,
                                    gw2, gb2, mw2t, mb2, prev, out, N, E);
}

// Round 6
// 559.068 us; speedup vs baseline: 1.5915x; 1.1193x over previous
//
#include <hip/hip_runtime.h>
#include <hip/hip_bf16.h>

typedef __bf16 bf16x8 __attribute__((ext_vector_type(8)));
typedef float f32x4 __attribute__((ext_vector_type(4)));

#define WIN 64           // edge-position window per block (segment starts)
#define TILE 112         // WIN-1 + max_degree(<=49)
#define LSTR 136         // bf16 row stride (272B): 16B aligned, bank-shift 4/row
#define SCAN_BLK 1024
#define SENT 0x7f7f7f7f

// weights conversion + all buffer inits (replaces 3 memsets)
// Bt[c][k] (512x64): c<128 gw1_top, <256 gw1_bot, <384 mw1_top, else mw1_bot.
// mw2t[c][k] (64x128) for GEMM2.
__global__ void k_wconv(const float* __restrict__ gw1, const float* __restrict__ mw1,
                        const float* __restrict__ mw2,
                        __bf16* __restrict__ Bt, __bf16* __restrict__ mw2t,
                        int* __restrict__ hist, int* __restrict__ s_lo,
                        int* __restrict__ s_hi, int N, int NB)
{
    int i = blockIdx.x * 256 + threadIdx.x;
    if (i < 32768) {
        int c = i >> 6, k = i & 63;
        float v;
        if (c < 128)      v = gw1[k * 128 + c];
        else if (c < 256) v = gw1[(64 + k) * 128 + (c - 128)];
        else if (c < 384) v = mw1[k * 128 + (c - 256)];
        else              v = mw1[(64 + k) * 128 + (c - 384)];
        Bt[i] = (__bf16)v;
    } else if (i < 40960) {
        int j = i - 32768;
        int c = j >> 7, k = j & 127;
        mw2t[j] = (__bf16)mw2[k * 64 + c];
    }
    if (i < N) hist[i] = 0;
    if (i < NB) { s_lo[i] = SENT; s_hi[i] = 0; }
}

// Split tables: Tp[n][256] = [Pg|Pm] (self part, biases folded),
//               Tq[n][256] = [Qg|Qm] (neighbor part). Fused: edge histogram.
__global__ void __launch_bounds__(256, 4)
k_tab(const float* __restrict__ feat, const __bf16* __restrict__ Bt,
      const float* __restrict__ gb1, const float* __restrict__ mb1,
      const int* __restrict__ selfi, int* __restrict__ hist,
      __bf16* __restrict__ Tp, __bf16* __restrict__ Tq, int N, int E)
{
    for (int e = blockIdx.x * 256 + threadIdx.x; e < E; e += gridDim.x * 256)
        atomicAdd(&hist[selfi[e]], 1);

    const int tid = threadIdx.x;
    const int lane = tid & 63, wv = tid >> 6;
    const int la = lane & 15, kg = lane >> 4;
    const int r0 = blockIdx.x * 16;
    if (r0 >= N) return;

    bf16x8 a[2];
    #pragma unroll
    for (int kk = 0; kk < 2; ++kk) {
        const int rr = min(r0 + la, N - 1);
        const float* src = feat + (size_t)rr * 64 + kk * 32 + kg * 8;
        f32x4 f0 = *reinterpret_cast<const f32x4*>(src);
        f32x4 f1 = *reinterpret_cast<const f32x4*>(src + 4);
        #pragma unroll
        for (int j = 0; j < 4; ++j) { a[kk][j] = (__bf16)f0[j]; a[kk][4 + j] = (__bf16)f1[j]; }
    }
    #pragma unroll
    for (int j = 0; j < 8; ++j) {
        const int c = wv * 128 + j * 16 + la;
        float bias = 0.f;
        if (c < 128) bias = gb1[c];
        else if (c >= 256 && c < 384) bias = mb1[c - 256];
        f32x4 acc = {bias, bias, bias, bias};
        #pragma unroll
        for (int kk = 0; kk < 2; ++kk) {
            bf16x8 bb = *reinterpret_cast<const bf16x8*>(Bt + (size_t)c * 64 + kk * 32 + kg * 8);
            acc = __builtin_amdgcn_mfma_f32_16x16x32_bf16(a[kk], bb, acc, 0, 0, 0);
        }
        #pragma unroll
        for (int i = 0; i < 4; ++i) {
            const int row = r0 + kg * 4 + i;
            if (row < N) {
                const __bf16 v = (__bf16)acc[i];
                if (c < 128)      Tp[(size_t)row * 256 + c] = v;
                else if (c < 256) Tq[(size_t)row * 256 + (c - 128)] = v;
                else if (c < 384) Tp[(size_t)row * 256 + 128 + (c - 256)] = v;
                else              Tq[(size_t)row * 256 + 128 + (c - 384)] = v;
            }
        }
    }
}

__global__ void k_scan1(const int* __restrict__ hist, int* __restrict__ incl,
                        int* __restrict__ bsum, int N)
{
    __shared__ int sd[SCAN_BLK];
    int i = blockIdx.x * SCAN_BLK + threadIdx.x;
    int v = (i < N) ? hist[i] : 0;
    sd[threadIdx.x] = v;
    __syncthreads();
    for (int off = 1; off < SCAN_BLK; off <<= 1) {
        int t = (threadIdx.x >= off) ? sd[threadIdx.x - off] : 0;
        __syncthreads();
        sd[threadIdx.x] += t;
        __syncthreads();
    }
    if (i < N) incl[i] = sd[threadIdx.x];
    if (threadIdx.x == SCAN_BLK - 1) bsum[blockIdx.x] = sd[SCAN_BLK - 1];
}

// merged: scan finalize + block meta + wp precompute + zero-degree out copy
__global__ void k_scan23(const int* __restrict__ incl, const int* __restrict__ hist,
                         const int* __restrict__ bsum,
                         int* __restrict__ cursor, int* __restrict__ starts,
                         int* __restrict__ s_lo, int* __restrict__ s_hi,
                         float* __restrict__ wp, const float* __restrict__ nodew,
                         const float* __restrict__ powp,
                         const float* __restrict__ prev, float* __restrict__ out,
                         int N, int E)
{
    __shared__ int boff_s;
    if (threadIdx.x == 0) {
        int run = 0;
        for (int j = 0; j < (int)blockIdx.x; ++j) run += bsum[j];
        boff_s = run;
    }
    __syncthreads();
    int i = blockIdx.x * SCAN_BLK + threadIdx.x;
    if (i >= N) return;
    const int h = hist[i];
    const int v = incl[i] - h + boff_s;
    cursor[i] = v;
    starts[i] = v;
    wp[i] = __powf(nodew[i], powp[0]);
    if (h > 0) {
        const int b = v / WIN;
        atomicMin(&s_lo[b], i);
        atomicMax(&s_hi[b], i + 1);
    } else {
        const float* ps = prev + (size_t)i * 64;
        float* po = out + (size_t)i * 64;
        for (int k = 0; k < 64; ++k) po[k] = ps[k];
    }
}

__global__ void k_scatter(const int* __restrict__ selfi, const int* __restrict__ nbri,
                          int* __restrict__ cursor, int2* __restrict__ edge_p, int E)
{
    int e = blockIdx.x * 256 + threadIdx.x;
    if (e >= E) return;
    int s = selfi[e];
    int pos = atomicAdd(&cursor[s], 1);
    edge_p[pos] = make_int2(s, nbri[e]);
}

// ---- fused edge kernel ----
__global__ void __launch_bounds__(256, 5)
k_fused(const __bf16* __restrict__ Tp, const __bf16* __restrict__ Tq,
        const int2* __restrict__ edge_p, const int* __restrict__ starts,
        const int* __restrict__ s_lo, const int* __restrict__ s_hi,
        const float* __restrict__ wp,
        const float* __restrict__ gw2, const float* __restrict__ gb2,
        const __bf16* __restrict__ mw2t, const float* __restrict__ mb2,
        const float* __restrict__ prev, float* __restrict__ out,
        int N, int E)
{
    __shared__ __align__(16) __bf16 hlds[TILE][LSTR];  // h (bf16) -> xb f32 [TILE][68]
    __shared__ int2 edge_s[TILE];
    __shared__ float logit_s[TILE];                    // raw logit -> unnormalized g
    __shared__ float nbrw_s[TILE];                     // w^p per edge
    __shared__ float ginv_s[WIN];                      // 1/(gsum+eps) per segment

    const int b = blockIdx.x;
    const int s0 = s_lo[b];
    if (s0 == SENT) return;
    const int s1 = s_hi[b];
    const int e0 = starts[s0];
    const int e1 = (s1 < N) ? starts[s1] : E;
    int ne = e1 - e0;
    if (ne > TILE) ne = TILE;   // safety clamp

    const int tid = threadIdx.x;
    for (int i = tid; i < ne; i += 256) {
        const int2 eg = edge_p[e0 + i];
        edge_s[i] = eg;
        nbrw_s[i] = wp[eg.y];
    }
    __syncthreads();

    const int lane = tid & 63, wv = tid >> 6;
    const int g16 = tid >> 4, il = tid & 15;

    // ---- phase 1: 16-lane edge groups, contiguous chunk, prefetch distance 2 ----
    {
        const float b2v = gb2[0];
        float w2f[8];
        {
            f32x4 wa = *reinterpret_cast<const f32x4*>(gw2 + il * 8);
            f32x4 wb = *reinterpret_cast<const f32x4*>(gw2 + il * 8 + 4);
            w2f[0] = wa[0]; w2f[1] = wa[1]; w2f[2] = wa[2]; w2f[3] = wa[3];
            w2f[4] = wb[0]; w2f[5] = wb[1]; w2f[6] = wb[2]; w2f[7] = wb[3];
        }
        const int ck = (ne + 15) >> 4;
        const int rb = g16 * ck;
        const int re = min(rb + ck, ne);
        int prev_sn = -1;
        float pgf[8], pmf[8];
        #pragma unroll
        for (int j = 0; j < 8; ++j) { pgf[j] = 0.f; pmf[j] = 0.f; }

        int2 eA = make_int2(0, 0), eB = make_int2(0, 0);
        bf16x8 qgA = {}, qmA = {}, qgB = {}, qmB = {};
        if (rb < re) {
            eA = edge_s[rb];
            const __bf16* tq = Tq + (size_t)eA.y * 256 + il * 8;
            qgA = *reinterpret_cast<const bf16x8*>(tq);
            qmA = *reinterpret_cast<const bf16x8*>(tq + 128);
        }
        if (rb + 1 < re) {
            eB = edge_s[rb + 1];
            const __bf16* tq = Tq + (size_t)eB.y * 256 + il * 8;
            qgB = *reinterpret_cast<const bf16x8*>(tq);
            qmB = *reinterpret_cast<const bf16x8*>(tq + 128);
        }
        for (int r = rb; r < re; r += 2) {
            // prefetch r+2 into fresh slot
            int2 eA2 = make_int2(0, 0);
            bf16x8 qgA2 = {}, qmA2 = {};
            if (r + 2 < re) {
                eA2 = edge_s[r + 2];
                const __bf16* tq = Tq + (size_t)eA2.y * 256 + il * 8;
                qgA2 = *reinterpret_cast<const bf16x8*>(tq);
                qmA2 = *reinterpret_cast<const bf16x8*>(tq + 128);
            }
            // compute edge r (slot A)
            if (eA.x != prev_sn) {
                const __bf16* tp = Tp + (size_t)eA.x * 256 + il * 8;
                bf16x8 pg = *reinterpret_cast<const bf16x8*>(tp);
                bf16x8 pm = *reinterpret_cast<const bf16x8*>(tp + 128);
                #pragma unroll
                for (int j = 0; j < 8; ++j) { pgf[j] = (float)pg[j]; pmf[j] = (float)pm[j]; }
                prev_sn = eA.x;
            }
            {
                float lg = 0.f;
                bf16x8 hv;
                #pragma unroll
                for (int j = 0; j < 8; ++j) {
                    lg = fmaf(fmaxf(pgf[j] + (float)qgA[j], 0.f), w2f[j], lg);
                    hv[j] = (__bf16)fmaxf(pmf[j] + (float)qmA[j], 0.f);
                }
                *reinterpret_cast<bf16x8*>(&hlds[r][il * 8]) = hv;
                #pragma unroll
                for (int sh = 1; sh < 16; sh <<= 1)
                    lg += __shfl_xor(lg, sh, 16);
                if (il == 0) logit_s[r] = lg + b2v;
            }
            // prefetch r+3 into fresh slot
            int2 eB2 = make_int2(0, 0);
            bf16x8 qgB2 = {}, qmB2 = {};
            if (r + 3 < re) {
                eB2 = edge_s[r + 3];
                const __bf16* tq = Tq + (size_t)eB2.y * 256 + il * 8;
                qgB2 = *reinterpret_cast<const bf16x8*>(tq);
                qmB2 = *reinterpret_cast<const bf16x8*>(tq + 128);
            }
            // compute edge r+1 (slot B)
            if (r + 1 < re) {
                if (eB.x != prev_sn) {
                    const __bf16* tp = Tp + (size_t)eB.x * 256 + il * 8;
                    bf16x8 pg = *reinterpret_cast<const bf16x8*>(tp);
                    bf16x8 pm = *reinterpret_cast<const bf16x8*>(tp + 128);
                    #pragma unroll
                    for (int j = 0; j < 8; ++j) { pgf[j] = (float)pg[j]; pmf[j] = (float)pm[j]; }
                    prev_sn = eB.x;
                }
                float lg = 0.f;
                bf16x8 hv;
                #pragma unroll
                for (int j = 0; j < 8; ++j) {
                    lg = fmaf(fmaxf(pgf[j] + (float)qgB[j], 0.f), w2f[j], lg);
                    hv[j] = (__bf16)fmaxf(pmf[j] + (float)qmB[j], 0.f);
                }
                *reinterpret_cast<bf16x8*>(&hlds[r + 1][il * 8]) = hv;
                #pragma unroll
                for (int sh = 1; sh < 16; sh <<= 1)
                    lg += __shfl_xor(lg, sh, 16);
                if (il == 0) logit_s[r + 1] = lg + b2v;
            }
            eA = eA2; qgA = qgA2; qmA = qmA2;
            eB = eB2; qgB = qgB2; qmB = qmB2;
        }
    }
    __syncthreads();

    // ---- phase 3a: GEMM2 x = h @ mw2 (issued first so MFMA overlaps softmax VALU) ----
    const int la = lane & 15, kg = lane >> 4;
    const int row0[2] = {wv * 16, 64 + wv * 16};
    const bool lv[2] = {row0[0] < ne, (wv < 3) && (row0[1] < ne)};

    f32x4 c2[2][4] = {};
    #pragma unroll
    for (int kk = 0; kk < 4; ++kk) {
        const int kbase = kk * 32 + kg * 8;
        bf16x8 a[2];
        #pragma unroll
        for (int m = 0; m < 2; ++m)
            if (lv[m]) a[m] = *reinterpret_cast<const bf16x8*>(&hlds[row0[m] + la][kbase]);
        #pragma unroll
        for (int n = 0; n < 4; ++n) {
            bf16x8 bb = *reinterpret_cast<const bf16x8*>(mw2t + (size_t)(n * 16 + la) * 128 + kbase);
            #pragma unroll
            for (int m = 0; m < 2; ++m)
                if (lv[m]) c2[m][n] = __builtin_amdgcn_mfma_f32_16x16x32_bf16(a[m], bb, c2[m][n], 0, 0, 0);
        }
    }

    // ---- phase 2: segment softmax numerators (16-lane groups, 4 segs/wave) ----
    for (int j = g16; j < s1 - s0; j += 16) {
        const int s = s0 + j;
        int a0 = starts[s] - e0;
        int a1 = ((s + 1 < N) ? starts[s + 1] : E) - e0;
        if (a1 > ne) a1 = ne;
        float mx = -3.4e38f;
        for (int idx = a0 + il; idx < a1; idx += 16)
            mx = fmaxf(mx, logit_s[idx]);
        #pragma unroll
        for (int sh = 1; sh < 16; sh <<= 1)
            mx = fmaxf(mx, __shfl_xor(mx, sh, 16));
        float sum = 0.f;
        for (int idx = a0 + il; idx < a1; idx += 16) {
            const float g = nbrw_s[idx] * __expf(logit_s[idx] - mx);
            logit_s[idx] = g;
            sum += g;
        }
        #pragma unroll
        for (int sh = 1; sh < 16; sh <<= 1)
            sum += __shfl_xor(sum, sh, 16);
        if (il == 0) ginv_s[j] = 1.f / (sum + 1e-10f);
    }
    __syncthreads();   // logit_s = g; ginv_s ready; all GEMM2 hlds reads done

    // ---- gated (unnormalized) message -> f32 xb (aliases hlds) ----
    float (*xb)[68] = reinterpret_cast<float(*)[68]>(&hlds[0][0]);
    #pragma unroll
    for (int m = 0; m < 2; ++m) {
        if (!lv[m]) continue;
        float cf[4];
        #pragma unroll
        for (int i = 0; i < 4; ++i) {
            const int row = row0[m] + kg * 4 + i;
            cf[i] = (row < ne) ? logit_s[row] : 0.f;
        }
        #pragma unroll
        for (int n = 0; n < 4; ++n) {
            const float b2v = mb2[n * 16 + la];
            #pragma unroll
            for (int i = 0; i < 4; ++i)
                xb[row0[m] + kg * 4 + i][n * 16 + la] = cf[i] * (c2[m][n][i] + b2v);
        }
    }
    __syncthreads();

    // ---- per-segment column sum, normalize once, non-atomic store ----
    for (int s = s0 + wv; s < s1; s += 4) {
        int a0 = starts[s] - e0;
        int a1 = ((s + 1 < N) ? starts[s + 1] : E) - e0;
        if (a1 > ne) a1 = ne;
        if (a1 <= a0) continue;
        float sum = 0.f;
        for (int r = a0; r < a1; ++r) sum += xb[r][lane];
        const float gi = ginv_s[s - s0];
        const size_t o = (size_t)s * 64 + lane;
        out[o] = prev[o] + sum * gi;
    }
}

extern "C" void kernel_launch(void* const* d_in, const int* in_sizes, int n_in,
                              void* d_out, int out_size, void* d_ws, size_t ws_size,
                              hipStream_t stream)
{
    const float* node_w = (const float*)d_in[0];
    const float* prev   = (const float*)d_in[1];
    const int*   selfi  = (const int*)d_in[2];
    const int*   nbri   = (const int*)d_in[3];
    const float* gw1 = (const float*)d_in[4];
    const float* gb1 = (const float*)d_in[5];
    const float* gw2 = (const float*)d_in[6];
    const float* gb2 = (const float*)d_in[7];
    const float* mw1 = (const float*)d_in[8];
    const float* mb1 = (const float*)d_in[9];
    const float* mw2 = (const float*)d_in[10];
    const float* mb2 = (const float*)d_in[11];
    const float* powp = (const float*)d_in[12];
    const int N = in_sizes[0];
    const int E = in_sizes[2];
    float* out = (float*)d_out;
    const int NB = (E + WIN - 1) / WIN;

    char* ws = (char*)d_ws;
    size_t off = 0;
    auto alloc = [&](size_t bytes) {
        void* p = ws + off;
        off = (off + bytes + 255) & ~(size_t)255;
        return p;
    };
    __bf16* Tp     = (__bf16*)alloc((size_t)N * 256 * 2);   // 51.2 MB
    __bf16* Tq     = (__bf16*)alloc((size_t)N * 256 * 2);   // 51.2 MB
    __bf16* Bt     = (__bf16*)alloc(512 * 64 * 2);
    __bf16* mw2t   = (__bf16*)alloc(64 * 128 * 2);
    int2* edge_p   = (int2*)alloc((size_t)E * 8);
    int* hist      = (int*)alloc((size_t)N * 4);
    int* cursor    = (int*)alloc((size_t)N * 4);
    int* starts    = (int*)alloc((size_t)N * 4);
    int* incl      = (int*)alloc((size_t)N * 4);
    float* wp      = (float*)alloc((size_t)N * 4);
    int* s_lo      = (int*)alloc((size_t)NB * 4);
    int* s_hi      = (int*)alloc((size_t)NB * 4);
    const int nb = (N + SCAN_BLK - 1) / SCAN_BLK;
    int* bsum      = (int*)alloc((size_t)nb * 4);

    const int initN = (N > 40960) ? N : 40960;
    k_wconv<<<(initN + 255) / 256, 256, 0, stream>>>(gw1, mw1, mw2, Bt, mw2t,
                                                     hist, s_lo, s_hi, N, NB);
    k_tab<<<(N + 15) / 16, 256, 0, stream>>>(prev, Bt, gb1, mb1, selfi, hist, Tp, Tq, N, E);
    k_scan1<<<nb, SCAN_BLK, 0, stream>>>(hist, incl, bsum, N);
    k_scan23<<<nb, SCAN_BLK, 0, stream>>>(incl, hist, bsum, cursor, starts, s_lo, s_hi,
                                          wp, node_w, powp, prev, out, N, E);
    k_scatter<<<(E + 255) / 256, 256, 0, stream>>>(selfi, nbri, cursor, edge_p, E);
    k_fused<<<NB, 256, 0, stream>>>(Tp, Tq, edge_p, starts, s_lo, s_hi, wp,
                                    gw2, gb2, mw2t, mb2, prev, out, N, E);
}